// Round 2
// baseline (212.391 us; speedup 1.0000x reference)
//
#include <hip/hip_runtime.h>
#include <hip/hip_bf16.h>
#include <math.h>

typedef short s16x8 __attribute__((ext_vector_type(8)));
typedef float f32x4 __attribute__((ext_vector_type(4)));
typedef unsigned short u16;

#define NHEADS 12
#define SEQ 2048
#define NBH 24          // B*H
#define KDIM 768

static __device__ __forceinline__ u16 f2bf(float f) {
    union { float f; unsigned u; } v; v.f = f;
    unsigned r = v.u + 0x7fffu + ((v.u >> 16) & 1u);
    return (u16)(r >> 16);
}

// ---------------- f32 -> bf16 convert ----------------
__global__ void cvt_kernel(const float* __restrict__ src, u16* __restrict__ dst, int n4) {
    int i = blockIdx.x * blockDim.x + threadIdx.x;
    if (i < n4) {
        float4 f = ((const float4*)src)[i];
        ushort4 o;
        o.x = f2bf(f.x); o.y = f2bf(f.y); o.z = f2bf(f.z); o.w = f2bf(f.w);
        ((ushort4*)dst)[i] = o;
    }
}

// ---------------- QKV projection GEMM ----------------
// y[m,n] = sum_k A[m,k] * W[n,k] + bias[n]   (torch Linear, W row-major [N][K])
// out scattered to [b, h, s, d] bf16 (bh-major) for the attention kernel.
__launch_bounds__(256)
__global__ void qkv_gemm(const u16* __restrict__ X, const u16* __restrict__ C,
                         const u16* __restrict__ W0, const u16* __restrict__ W1, const u16* __restrict__ W2,
                         const float* __restrict__ b0, const float* __restrict__ b1, const float* __restrict__ b2,
                         u16* __restrict__ Qo, u16* __restrict__ Ko, u16* __restrict__ Vo) {
    const int z = blockIdx.z;
    const u16* A    = (z == 0) ? X  : C;
    const u16* W    = (z == 0) ? W0 : (z == 1) ? W1 : W2;
    const float* bi = (z == 0) ? b0 : (z == 1) ? b1 : b2;
    u16* out        = (z == 0) ? Qo : (z == 1) ? Ko : Vo;

    __shared__ u16 As[128][64];
    __shared__ u16 Bs[128][64];

    const int tid  = threadIdx.x;
    const int lane = tid & 63;
    const int wid  = tid >> 6;
    const int wr = wid >> 1, wc = wid & 1;
    const int l15 = lane & 15, lh = lane >> 4;
    const int mBase = blockIdx.x * 128;
    const int nBase = blockIdx.y * 128;

    f32x4 acc[4][4] = {};

    for (int kb = 0; kb < KDIM; kb += 64) {
        __syncthreads();
        #pragma unroll
        for (int i = 0; i < 4; ++i) {
            int c = tid + 256 * i;
            int row = c >> 3, c8 = (c & 7) * 8;
            *(s16x8*)(&As[row][c8]) = *(const s16x8*)(&A[(size_t)(mBase + row) * KDIM + kb + c8]);
            *(s16x8*)(&Bs[row][c8]) = *(const s16x8*)(&W[(size_t)(nBase + row) * KDIM + kb + c8]);
        }
        __syncthreads();
        #pragma unroll
        for (int kk = 0; kk < 2; ++kk) {
            s16x8 af[4], bf[4];
            #pragma unroll
            for (int m = 0; m < 4; ++m)
                af[m] = *(const s16x8*)(&As[wr * 64 + m * 16 + l15][kk * 32 + lh * 8]);
            #pragma unroll
            for (int n = 0; n < 4; ++n)
                bf[n] = *(const s16x8*)(&Bs[wc * 64 + n * 16 + l15][kk * 32 + lh * 8]);
            #pragma unroll
            for (int m = 0; m < 4; ++m)
                #pragma unroll
                for (int n = 0; n < 4; ++n)
                    acc[m][n] = __builtin_amdgcn_mfma_f32_16x16x32_bf16(af[m], bf[n], acc[m][n], 0, 0, 0);
        }
    }

    #pragma unroll
    for (int m = 0; m < 4; ++m) {
        #pragma unroll
        for (int n = 0; n < 4; ++n) {
            int colg = nBase + wc * 64 + n * 16 + l15;
            float bv = bi[colg];
            int h = colg >> 6, d = colg & 63;
            #pragma unroll
            for (int j = 0; j < 4; ++j) {
                int rowg = mBase + wr * 64 + m * 16 + lh * 4 + j;
                int b = rowg >> 11, s = rowg & 2047;
                out[(((size_t)(b * NHEADS + h) * SEQ + s) << 6) + d] = f2bf(acc[m][n][j] + bv);
            }
        }
    }
}

// ---------------- flash attention ----------------
// grid: (SEQ/64, NBH). 4 waves x 16 q-rows. KV tile = 64.
__launch_bounds__(256)
__global__ void attn_kernel(const u16* __restrict__ Qg, const u16* __restrict__ Kg, const u16* __restrict__ Vg,
                            const float* __restrict__ mask, float* __restrict__ out, float inv_s) {
    __shared__ u16 Ks[64][64];
    __shared__ u16 Vt[64][64];     // [d][kv]
    __shared__ u16 Ps[4][16][64];  // per-wave P tile

    const int tid  = threadIdx.x;
    const int lane = tid & 63;
    const int wid  = tid >> 6;
    const int bh = blockIdx.y;
    const int b = bh / NHEADS;
    const int h = bh % NHEADS;
    const int q0 = blockIdx.x * 64 + wid * 16;
    const int l15 = lane & 15, lh = lane >> 4;

    // Q fragments (hoisted): lane holds Q[q0+l15][kk*32 + lh*8 .. +7]
    s16x8 qf[2];
    #pragma unroll
    for (int kk = 0; kk < 2; ++kk)
        qf[kk] = *(const s16x8*)(&Qg[(((size_t)bh * SEQ + q0 + l15) << 6) + kk * 32 + lh * 8]);

    f32x4 oacc[4] = {};
    float mrun[4], lrun[4];
    #pragma unroll
    for (int j = 0; j < 4; ++j) { mrun[j] = -1e30f; lrun[j] = 0.f; }

    for (int kb = 0; kb < SEQ; kb += 64) {
        __syncthreads();
        #pragma unroll
        for (int i = 0; i < 2; ++i) {
            int c = tid + 256 * i;
            int row = c >> 3, c8 = (c & 7) * 8;
            *(s16x8*)(&Ks[row][c8]) = *(const s16x8*)(&Kg[(((size_t)bh * SEQ + kb + row) << 6) + c8]);
            s16x8 v8 = *(const s16x8*)(&Vg[(((size_t)bh * SEQ + kb + row) << 6) + c8]);
            #pragma unroll
            for (int e = 0; e < 8; ++e) Vt[c8 + e][row] = ((u16*)&v8)[e];
        }
        __syncthreads();

        // scores: S[q][kv] = sum_d Q K
        f32x4 sacc[4] = {};
        #pragma unroll
        for (int kk = 0; kk < 2; ++kk) {
            #pragma unroll
            for (int n = 0; n < 4; ++n) {
                s16x8 kf = *(const s16x8*)(&Ks[n * 16 + l15][kk * 32 + lh * 8]);
                sacc[n] = __builtin_amdgcn_mfma_f32_16x16x32_bf16(qf[kk], kf, sacc[n], 0, 0, 0);
            }
        }
        float mv[4];
        #pragma unroll
        for (int n = 0; n < 4; ++n) mv[n] = mask[b * SEQ + kb + n * 16 + l15];
        #pragma unroll
        for (int n = 0; n < 4; ++n)
            #pragma unroll
            for (int j = 0; j < 4; ++j)
                sacc[n][j] = sacc[n][j] * inv_s + mv[n];

        // online softmax (wave-parallel: 16 lanes hold one row)
        float p[4][4];
        #pragma unroll
        for (int j = 0; j < 4; ++j) {
            float t = fmaxf(fmaxf(sacc[0][j], sacc[1][j]), fmaxf(sacc[2][j], sacc[3][j]));
            #pragma unroll
            for (int off = 1; off < 16; off <<= 1)
                t = fmaxf(t, __shfl_xor(t, off, 16));
            float mnew = fmaxf(mrun[j], t);
            float alpha = __expf(mrun[j] - mnew);
            float rs = 0.f;
            #pragma unroll
            for (int n = 0; n < 4; ++n) {
                p[n][j] = __expf(sacc[n][j] - mnew);
                rs += p[n][j];
            }
            #pragma unroll
            for (int off = 1; off < 16; off <<= 1)
                rs += __shfl_xor(rs, off, 16);
            lrun[j] = lrun[j] * alpha + rs;
            mrun[j] = mnew;
            #pragma unroll
            for (int n = 0; n < 4; ++n)
                oacc[n][j] *= alpha;
        }
        // P -> per-wave LDS (C-layout scatter), then read back in A-frag layout
        #pragma unroll
        for (int n = 0; n < 4; ++n)
            #pragma unroll
            for (int j = 0; j < 4; ++j)
                Ps[wid][lh * 4 + j][n * 16 + l15] = f2bf(p[n][j]);

        asm volatile("s_waitcnt lgkmcnt(0)" ::: "memory");
        __builtin_amdgcn_sched_barrier(0);

        // PV: ctx[q][d] += P[q][kv] * V[kv][d]
        #pragma unroll
        for (int kk = 0; kk < 2; ++kk) {
            s16x8 pf = *(const s16x8*)(&Ps[wid][l15][kk * 32 + lh * 8]);
            #pragma unroll
            for (int nd = 0; nd < 4; ++nd) {
                s16x8 vf = *(const s16x8*)(&Vt[nd * 16 + l15][kk * 32 + lh * 8]);
                oacc[nd] = __builtin_amdgcn_mfma_f32_16x16x32_bf16(pf, vf, oacc[nd], 0, 0, 0);
            }
        }
    }

    #pragma unroll
    for (int nd = 0; nd < 4; ++nd) {
        int d = nd * 16 + l15;
        #pragma unroll
        for (int j = 0; j < 4; ++j) {
            int s = q0 + lh * 4 + j;
            out[((size_t)(b * SEQ + s)) * (NHEADS * 64) + h * 64 + d] = oacc[nd][j] / lrun[j];
        }
    }
}

extern "C" void kernel_launch(void* const* d_in, const int* in_sizes, int n_in,
                              void* d_out, int out_size, void* d_ws, size_t ws_size,
                              hipStream_t stream) {
    const float* hidden  = (const float*)d_in[0];
    const float* context = (const float*)d_in[1];
    const float* mask    = (const float*)d_in[2];
    const float* Wq = (const float*)d_in[3];
    const float* bq = (const float*)d_in[4];
    const float* Wk = (const float*)d_in[5];
    const float* bk = (const float*)d_in[6];
    const float* Wv = (const float*)d_in[7];
    const float* bv = (const float*)d_in[8];
    float* out = (float*)d_out;

    char* ws = (char*)d_ws;
    const size_t XSZ = (size_t)4096 * 768 * 2;  // activations / per-tensor QKV, bytes
    const size_t WSZ = (size_t)768 * 768 * 2;   // one weight, bytes
    u16* X16  = (u16*)(ws);
    u16* C16  = (u16*)(ws + XSZ);
    u16* W16q = (u16*)(ws + 2 * XSZ);
    u16* W16k = (u16*)(ws + 2 * XSZ + WSZ);
    u16* W16v = (u16*)(ws + 2 * XSZ + 2 * WSZ);
    u16* Q16  = (u16*)(ws + 2 * XSZ + 3 * WSZ);
    u16* K16  = (u16*)(ws + 3 * XSZ + 3 * WSZ);
    u16* V16  = (u16*)(ws + 4 * XSZ + 3 * WSZ);

    const int n4x = 4096 * 768 / 4;
    const int n4w = 768 * 768 / 4;
    cvt_kernel<<<(n4x + 255) / 256, 256, 0, stream>>>(hidden,  X16, n4x);
    cvt_kernel<<<(n4x + 255) / 256, 256, 0, stream>>>(context, C16, n4x);
    cvt_kernel<<<(n4w + 255) / 256, 256, 0, stream>>>(Wq, W16q, n4w);
    cvt_kernel<<<(n4w + 255) / 256, 256, 0, stream>>>(Wk, W16k, n4w);
    cvt_kernel<<<(n4w + 255) / 256, 256, 0, stream>>>(Wv, W16v, n4w);

    qkv_gemm<<<dim3(4096 / 128, 768 / 128, 3), 256, 0, stream>>>(
        X16, C16, W16q, W16k, W16v, bq, bk, bv, Q16, K16, V16);

    float inv_s = (float)(1.0 / sqrt(64.0 + 1e-5));
    attn_kernel<<<dim3(SEQ / 64, NBH), 256, 0, stream>>>(Q16, K16, V16, mask, out, inv_s);
}

// Round 3
// 156.765 us; speedup vs baseline: 1.3548x; 1.3548x over previous
//
#include <hip/hip_runtime.h>
#include <hip/hip_bf16.h>
#include <math.h>

typedef short s16x8 __attribute__((ext_vector_type(8)));
typedef float f32x4 __attribute__((ext_vector_type(4)));
typedef unsigned short u16;

#define NHEADS 12
#define SEQ 2048
#define NBH 24          // B*H
#define KDIM 768

// XOR swizzle for u16 tiles with 64-u16 (128 B) rows: flip byte bits 4-6 by row&7.
// In u16 units: col ^ ((row&7)<<3). Keeps 16B alignment for 8-element accesses.
#define SWZ(row, col) (((row) * 64) + ((col) ^ (((row) & 7) << 3)))

static __device__ __forceinline__ u16 f2bf(float f) {
    union { float f; unsigned u; } v; v.f = f;
    unsigned r = v.u + 0x7fffu + ((v.u >> 16) & 1u);
    return (u16)(r >> 16);
}

// ---------------- f32 -> bf16 convert (fused: z selects tensor) ----------------
__global__ void cvt5_kernel(const float* __restrict__ s0, const float* __restrict__ s1,
                            const float* __restrict__ s2, const float* __restrict__ s3,
                            const float* __restrict__ s4,
                            u16* __restrict__ d0, u16* __restrict__ d1, u16* __restrict__ d2,
                            u16* __restrict__ d3, u16* __restrict__ d4,
                            int n4a, int n4w) {
    const int z = blockIdx.z;
    const float* src = (z == 0) ? s0 : (z == 1) ? s1 : (z == 2) ? s2 : (z == 3) ? s3 : s4;
    u16* dst         = (z == 0) ? d0 : (z == 1) ? d1 : (z == 2) ? d2 : (z == 3) ? d3 : d4;
    const int n4     = (z < 2) ? n4a : n4w;
    int i = blockIdx.x * blockDim.x + threadIdx.x;
    if (i < n4) {
        float4 f = ((const float4*)src)[i];
        ushort4 o;
        o.x = f2bf(f.x); o.y = f2bf(f.y); o.z = f2bf(f.z); o.w = f2bf(f.w);
        ((ushort4*)dst)[i] = o;
    }
}

// ---------------- QKV projection GEMM ----------------
// y[m,n] = sum_k A[m,k] * W[n,k] + bias[n]   (torch Linear, W row-major [N][K])
// Q,K out: [bh][s][d] bf16.  V out: TRANSPOSED [bh][d][s] bf16 for the PV B-operand.
__launch_bounds__(256)
__global__ void qkv_gemm(const u16* __restrict__ X, const u16* __restrict__ C,
                         const u16* __restrict__ W0, const u16* __restrict__ W1, const u16* __restrict__ W2,
                         const float* __restrict__ b0, const float* __restrict__ b1, const float* __restrict__ b2,
                         u16* __restrict__ Qo, u16* __restrict__ Ko, u16* __restrict__ Vo) {
    const int z = blockIdx.z;
    const u16* A    = (z == 0) ? X  : C;
    const u16* W    = (z == 0) ? W0 : (z == 1) ? W1 : W2;
    const float* bi = (z == 0) ? b0 : (z == 1) ? b1 : b2;
    u16* out        = (z == 0) ? Qo : (z == 1) ? Ko : Vo;

    __shared__ u16 As[128 * 64];
    __shared__ u16 Bs[128 * 64];

    const int tid  = threadIdx.x;
    const int lane = tid & 63;
    const int wid  = tid >> 6;
    const int wr = wid >> 1, wc = wid & 1;
    const int l15 = lane & 15, lh = lane >> 4;
    const int mBase = blockIdx.x * 128;
    const int nBase = blockIdx.y * 128;

    f32x4 acc[4][4] = {};

    for (int kb = 0; kb < KDIM; kb += 64) {
        __syncthreads();
        #pragma unroll
        for (int i = 0; i < 4; ++i) {
            int c = tid + 256 * i;
            int row = c >> 3, c8 = (c & 7) * 8;
            *(s16x8*)(&As[SWZ(row, c8)]) = *(const s16x8*)(&A[(size_t)(mBase + row) * KDIM + kb + c8]);
            *(s16x8*)(&Bs[SWZ(row, c8)]) = *(const s16x8*)(&W[(size_t)(nBase + row) * KDIM + kb + c8]);
        }
        __syncthreads();
        #pragma unroll
        for (int kk = 0; kk < 2; ++kk) {
            s16x8 af[4], bf[4];
            #pragma unroll
            for (int m = 0; m < 4; ++m)
                af[m] = *(const s16x8*)(&As[SWZ(wr * 64 + m * 16 + l15, kk * 32 + lh * 8)]);
            #pragma unroll
            for (int n = 0; n < 4; ++n)
                bf[n] = *(const s16x8*)(&Bs[SWZ(wc * 64 + n * 16 + l15, kk * 32 + lh * 8)]);
            #pragma unroll
            for (int m = 0; m < 4; ++m)
                #pragma unroll
                for (int n = 0; n < 4; ++n)
                    acc[m][n] = __builtin_amdgcn_mfma_f32_16x16x32_bf16(af[m], bf[n], acc[m][n], 0, 0, 0);
        }
    }

    if (z < 2) {
        #pragma unroll
        for (int m = 0; m < 4; ++m) {
            #pragma unroll
            for (int n = 0; n < 4; ++n) {
                int colg = nBase + wc * 64 + n * 16 + l15;
                float bv = bi[colg];
                int h = colg >> 6, d = colg & 63;
                #pragma unroll
                for (int j = 0; j < 4; ++j) {
                    int rowg = mBase + wr * 64 + m * 16 + lh * 4 + j;
                    int b = rowg >> 11, s = rowg & 2047;
                    out[(((size_t)(b * NHEADS + h) * SEQ + s) << 6) + d] = f2bf(acc[m][n][j] + bv);
                }
            }
        }
    } else {
        // V: write transposed [bh][d][s]; j-loop spans 4 consecutive s -> one ushort4.
        #pragma unroll
        for (int m = 0; m < 4; ++m) {
            #pragma unroll
            for (int n = 0; n < 4; ++n) {
                int colg = nBase + wc * 64 + n * 16 + l15;
                float bv = bi[colg];
                int h = colg >> 6, d = colg & 63;
                int rowg0 = mBase + wr * 64 + m * 16 + lh * 4;
                int b = rowg0 >> 11, s = rowg0 & 2047;
                ushort4 o;
                o.x = f2bf(acc[m][n][0] + bv);
                o.y = f2bf(acc[m][n][1] + bv);
                o.z = f2bf(acc[m][n][2] + bv);
                o.w = f2bf(acc[m][n][3] + bv);
                *(ushort4*)(&out[(((size_t)(b * NHEADS + h) * 64 + d) << 11) + s]) = o;
            }
        }
    }
}

// ---------------- flash attention ----------------
// grid: (SEQ/64, NBH). 4 waves x 16 q-rows. KV tile = 64.
// Vg is pre-transposed [bh][d][s].
__launch_bounds__(256)
__global__ void attn_kernel(const u16* __restrict__ Qg, const u16* __restrict__ Kg, const u16* __restrict__ Vg,
                            const float* __restrict__ mask, float* __restrict__ out, float inv_s) {
    __shared__ u16 Ks[64 * 64];
    __shared__ u16 Vt[64 * 64];      // [d][kv], swizzled
    __shared__ u16 Ps[4 * 16 * 64];  // per-wave P tile, swizzled

    const int tid  = threadIdx.x;
    const int lane = tid & 63;
    const int wid  = tid >> 6;
    const int bh = blockIdx.y;
    const int b = bh / NHEADS;
    const int q0 = blockIdx.x * 64 + wid * 16;
    const int h = bh % NHEADS;
    const int l15 = lane & 15, lh = lane >> 4;

    // Q fragments (hoisted): lane holds Q[q0+l15][kk*32 + lh*8 .. +7]
    s16x8 qf[2];
    #pragma unroll
    for (int kk = 0; kk < 2; ++kk)
        qf[kk] = *(const s16x8*)(&Qg[(((size_t)bh * SEQ + q0 + l15) << 6) + kk * 32 + lh * 8]);

    f32x4 oacc[4] = {};
    float mrun[4], lrun[4];
    #pragma unroll
    for (int j = 0; j < 4; ++j) { mrun[j] = -1e30f; lrun[j] = 0.f; }

    for (int kb = 0; kb < SEQ; kb += 64) {
        __syncthreads();
        #pragma unroll
        for (int i = 0; i < 2; ++i) {
            int c = tid + 256 * i;
            int row = c >> 3, c8 = (c & 7) * 8;
            *(s16x8*)(&Ks[SWZ(row, c8)]) = *(const s16x8*)(&Kg[(((size_t)bh * SEQ + kb + row) << 6) + c8]);
            // Vt tile: row = d (0..63), cols = kv; Vg pre-transposed [bh][d][2048]
            *(s16x8*)(&Vt[SWZ(row, c8)]) = *(const s16x8*)(&Vg[(((size_t)bh * 64 + row) << 11) + kb + c8]);
        }
        __syncthreads();

        // scores: S[q][kv] = sum_d Q K
        f32x4 sacc[4] = {};
        #pragma unroll
        for (int kk = 0; kk < 2; ++kk) {
            #pragma unroll
            for (int n = 0; n < 4; ++n) {
                s16x8 kf = *(const s16x8*)(&Ks[SWZ(n * 16 + l15, kk * 32 + lh * 8)]);
                sacc[n] = __builtin_amdgcn_mfma_f32_16x16x32_bf16(qf[kk], kf, sacc[n], 0, 0, 0);
            }
        }
        float mv[4];
        #pragma unroll
        for (int n = 0; n < 4; ++n) mv[n] = mask[b * SEQ + kb + n * 16 + l15];
        #pragma unroll
        for (int n = 0; n < 4; ++n)
            #pragma unroll
            for (int j = 0; j < 4; ++j)
                sacc[n][j] = sacc[n][j] * inv_s + mv[n];

        // online softmax (wave-parallel: 16 lanes hold one row)
        float p[4][4];
        #pragma unroll
        for (int j = 0; j < 4; ++j) {
            float t = fmaxf(fmaxf(sacc[0][j], sacc[1][j]), fmaxf(sacc[2][j], sacc[3][j]));
            #pragma unroll
            for (int off = 1; off < 16; off <<= 1)
                t = fmaxf(t, __shfl_xor(t, off, 16));
            float mnew = fmaxf(mrun[j], t);
            float alpha = __expf(mrun[j] - mnew);
            float rs = 0.f;
            #pragma unroll
            for (int n = 0; n < 4; ++n) {
                p[n][j] = __expf(sacc[n][j] - mnew);
                rs += p[n][j];
            }
            #pragma unroll
            for (int off = 1; off < 16; off <<= 1)
                rs += __shfl_xor(rs, off, 16);
            lrun[j] = lrun[j] * alpha + rs;
            mrun[j] = mnew;
            #pragma unroll
            for (int n = 0; n < 4; ++n)
                oacc[n][j] *= alpha;
        }
        // P -> per-wave LDS (C-layout scatter, swizzled), read back in A-frag layout
        #pragma unroll
        for (int n = 0; n < 4; ++n)
            #pragma unroll
            for (int j = 0; j < 4; ++j) {
                int prow = lh * 4 + j;
                Ps[wid * 1024 + SWZ(prow, n * 16 + l15)] = f2bf(p[n][j]);
            }

        asm volatile("s_waitcnt lgkmcnt(0)" ::: "memory");
        __builtin_amdgcn_sched_barrier(0);

        // PV: ctx[q][d] += P[q][kv] * V[kv][d]
        #pragma unroll
        for (int kk = 0; kk < 2; ++kk) {
            s16x8 pf = *(const s16x8*)(&Ps[wid * 1024 + SWZ(l15, kk * 32 + lh * 8)]);
            #pragma unroll
            for (int nd = 0; nd < 4; ++nd) {
                s16x8 vf = *(const s16x8*)(&Vt[SWZ(nd * 16 + l15, kk * 32 + lh * 8)]);
                oacc[nd] = __builtin_amdgcn_mfma_f32_16x16x32_bf16(pf, vf, oacc[nd], 0, 0, 0);
            }
        }
    }

    #pragma unroll
    for (int nd = 0; nd < 4; ++nd) {
        int d = nd * 16 + l15;
        #pragma unroll
        for (int j = 0; j < 4; ++j) {
            int s = q0 + lh * 4 + j;
            out[((size_t)(b * SEQ + s)) * (NHEADS * 64) + h * 64 + d] = oacc[nd][j] / lrun[j];
        }
    }
}

extern "C" void kernel_launch(void* const* d_in, const int* in_sizes, int n_in,
                              void* d_out, int out_size, void* d_ws, size_t ws_size,
                              hipStream_t stream) {
    const float* hidden  = (const float*)d_in[0];
    const float* context = (const float*)d_in[1];
    const float* mask    = (const float*)d_in[2];
    const float* Wq = (const float*)d_in[3];
    const float* bq = (const float*)d_in[4];
    const float* Wk = (const float*)d_in[5];
    const float* bk = (const float*)d_in[6];
    const float* Wv = (const float*)d_in[7];
    const float* bv = (const float*)d_in[8];
    float* out = (float*)d_out;

    char* ws = (char*)d_ws;
    const size_t XSZ = (size_t)4096 * 768 * 2;  // activations / per-tensor QKV, bytes
    const size_t WSZ = (size_t)768 * 768 * 2;   // one weight, bytes
    u16* X16  = (u16*)(ws);
    u16* C16  = (u16*)(ws + XSZ);
    u16* W16q = (u16*)(ws + 2 * XSZ);
    u16* W16k = (u16*)(ws + 2 * XSZ + WSZ);
    u16* W16v = (u16*)(ws + 2 * XSZ + 2 * WSZ);
    u16* Q16  = (u16*)(ws + 2 * XSZ + 3 * WSZ);
    u16* K16  = (u16*)(ws + 3 * XSZ + 3 * WSZ);
    u16* V16  = (u16*)(ws + 4 * XSZ + 3 * WSZ);  // transposed [bh][d][s]

    const int n4x = 4096 * 768 / 4;
    const int n4w = 768 * 768 / 4;
    cvt5_kernel<<<dim3((n4x + 255) / 256, 1, 5), 256, 0, stream>>>(
        hidden, context, Wq, Wk, Wv, X16, C16, W16q, W16k, W16v, n4x, n4w);

    qkv_gemm<<<dim3(4096 / 128, 768 / 128, 3), 256, 0, stream>>>(
        X16, C16, W16q, W16k, W16v, bq, bk, bv, Q16, K16, V16);

    float inv_s = (float)(1.0 / sqrt(64.0 + 1e-5));
    attn_kernel<<<dim3(SEQ / 64, NBH), 256, 0, stream>>>(Q16, K16, V16, mask, out, inv_s);
}

// Round 4
// 118.027 us; speedup vs baseline: 1.7995x; 1.3282x over previous
//
#include <hip/hip_runtime.h>
#include <hip/hip_bf16.h>
#include <math.h>

typedef short s16x8 __attribute__((ext_vector_type(8)));
typedef float f32x4 __attribute__((ext_vector_type(4)));
typedef _Float16 f16x4 __attribute__((ext_vector_type(4)));
typedef unsigned short u16;

#define NHEADS 12
#define SEQ 2048
#define NBH 24          // B*H
#define KDIM 768

// XOR swizzle for u16 tiles with 64-u16 (128 B) rows. Granularity 8 u16 (16 B),
// so 16B-contiguous chunks stay contiguous (global_load_lds compatible).
#define SWZ(row, col) (((row) * 64) + ((col) ^ (((row) & 7) << 3)))

// global -> LDS direct, 16B per lane. LDS dest = wave-uniform base + lane*16.
#define GLOAD_LDS16(g, l) __builtin_amdgcn_global_load_lds( \
    (const __attribute__((address_space(1))) unsigned int*)(g), \
    (__attribute__((address_space(3))) unsigned int*)(l), 16, 0, 0)

static __device__ __forceinline__ u16 f2bf(float f) {
    union { float f; unsigned u; } v; v.f = f;
    unsigned r = v.u + 0x7fffu + ((v.u >> 16) & 1u);
    return (u16)(r >> 16);
}
static __device__ __forceinline__ u16 f2h(float f) {
    union { _Float16 h; u16 u; } v; v.h = (_Float16)f;
    return v.u;
}

// ---------------- f32 -> bf16 convert (fused: z selects tensor) ----------------
__global__ void cvt5_kernel(const float* __restrict__ s0, const float* __restrict__ s1,
                            const float* __restrict__ s2, const float* __restrict__ s3,
                            const float* __restrict__ s4,
                            u16* __restrict__ d0, u16* __restrict__ d1, u16* __restrict__ d2,
                            u16* __restrict__ d3, u16* __restrict__ d4,
                            int n4a, int n4w) {
    const int z = blockIdx.z;
    const float* src = (z == 0) ? s0 : (z == 1) ? s1 : (z == 2) ? s2 : (z == 3) ? s3 : s4;
    u16* dst         = (z == 0) ? d0 : (z == 1) ? d1 : (z == 2) ? d2 : (z == 3) ? d3 : d4;
    const int n4     = (z < 2) ? n4a : n4w;
    int i = blockIdx.x * blockDim.x + threadIdx.x;
    if (i < n4) {
        float4 f = ((const float4*)src)[i];
        ushort4 o;
        o.x = f2bf(f.x); o.y = f2bf(f.y); o.z = f2bf(f.z); o.w = f2bf(f.w);
        ((ushort4*)dst)[i] = o;
    }
}

// ---------------- QKV projection GEMM ----------------
// y[m,n] = sum_k A[m,k] * W[n,k] + bias[n]   (torch Linear, W row-major [N][K])
// Q,K out: [bh][s][d] bf16.  V out: TRANSPOSED [bh][d][s] **f16** for the PV A-operand.
__launch_bounds__(256)
__global__ void qkv_gemm(const u16* __restrict__ X, const u16* __restrict__ C,
                         const u16* __restrict__ W0, const u16* __restrict__ W1, const u16* __restrict__ W2,
                         const float* __restrict__ b0, const float* __restrict__ b1, const float* __restrict__ b2,
                         u16* __restrict__ Qo, u16* __restrict__ Ko, u16* __restrict__ Vo) {
    const int z = blockIdx.z;
    const u16* A    = (z == 0) ? X  : C;
    const u16* W    = (z == 0) ? W0 : (z == 1) ? W1 : W2;
    const float* bi = (z == 0) ? b0 : (z == 1) ? b1 : b2;
    u16* out        = (z == 0) ? Qo : (z == 1) ? Ko : Vo;

    __shared__ u16 As[128 * 64];
    __shared__ u16 Bs[128 * 64];

    const int tid  = threadIdx.x;
    const int lane = tid & 63;
    const int wid  = tid >> 6;
    const int wr = wid >> 1, wc = wid & 1;
    const int l15 = lane & 15, lh = lane >> 4;
    const int mBase = blockIdx.x * 128;
    const int nBase = blockIdx.y * 128;

    // inverse-swizzled global sources, linear LDS dest (content = swizzled tile)
    size_t aSrc[4], bSrc[4]; int ldsOffG[4];
    #pragma unroll
    for (int i = 0; i < 4; ++i) {
        int L = wid * 512 + i * 2048 + lane * 8;
        int row = L >> 6;
        int col = (L & 63) ^ ((row & 7) << 3);
        aSrc[i] = (size_t)(mBase + row) * KDIM + col;
        bSrc[i] = (size_t)(nBase + row) * KDIM + col;
        ldsOffG[i] = wid * 512 + i * 2048;
    }

    f32x4 acc[4][4] = {};

    for (int kb = 0; kb < KDIM; kb += 64) {
        __syncthreads();
        #pragma unroll
        for (int i = 0; i < 4; ++i) {
            GLOAD_LDS16(&A[aSrc[i] + kb], &As[ldsOffG[i]]);
            GLOAD_LDS16(&W[bSrc[i] + kb], &Bs[ldsOffG[i]]);
        }
        __syncthreads();
        #pragma unroll
        for (int kk = 0; kk < 2; ++kk) {
            s16x8 af[4], bf[4];
            #pragma unroll
            for (int m = 0; m < 4; ++m)
                af[m] = *(const s16x8*)(&As[SWZ(wr * 64 + m * 16 + l15, kk * 32 + lh * 8)]);
            #pragma unroll
            for (int n = 0; n < 4; ++n)
                bf[n] = *(const s16x8*)(&Bs[SWZ(wc * 64 + n * 16 + l15, kk * 32 + lh * 8)]);
            #pragma unroll
            for (int m = 0; m < 4; ++m)
                #pragma unroll
                for (int n = 0; n < 4; ++n)
                    acc[m][n] = __builtin_amdgcn_mfma_f32_16x16x32_bf16(af[m], bf[n], acc[m][n], 0, 0, 0);
        }
    }

    if (z < 2) {
        #pragma unroll
        for (int m = 0; m < 4; ++m) {
            #pragma unroll
            for (int n = 0; n < 4; ++n) {
                int colg = nBase + wc * 64 + n * 16 + l15;
                float bv = bi[colg];
                int h = colg >> 6, d = colg & 63;
                #pragma unroll
                for (int j = 0; j < 4; ++j) {
                    int rowg = mBase + wr * 64 + m * 16 + lh * 4 + j;
                    int b = rowg >> 11, s = rowg & 2047;
                    out[(((size_t)(b * NHEADS + h) * SEQ + s) << 6) + d] = f2bf(acc[m][n][j] + bv);
                }
            }
        }
    } else {
        // V: write transposed [bh][d][s] as f16; 4 consecutive s -> one ushort4.
        #pragma unroll
        for (int m = 0; m < 4; ++m) {
            #pragma unroll
            for (int n = 0; n < 4; ++n) {
                int colg = nBase + wc * 64 + n * 16 + l15;
                float bv = bi[colg];
                int h = colg >> 6, d = colg & 63;
                int rowg0 = mBase + wr * 64 + m * 16 + lh * 4;
                int b = rowg0 >> 11, s = rowg0 & 2047;
                ushort4 o;
                o.x = f2h(acc[m][n][0] + bv);
                o.y = f2h(acc[m][n][1] + bv);
                o.z = f2h(acc[m][n][2] + bv);
                o.w = f2h(acc[m][n][3] + bv);
                *(ushort4*)(&out[(((size_t)(b * NHEADS + h) * 64 + d) << 11) + s]) = o;
            }
        }
    }
}

// ---------------- flash attention (swapped-QK^T, register softmax) ----------------
// grid: (SEQ/64, NBH). 4 waves x 16 q-rows (q = lane&15). KV tile = 64, double-buffered,
// one barrier per tile, global_load_lds prefetch in flight across the compute phase.
__launch_bounds__(256)
__global__ void attn_kernel(const u16* __restrict__ Qg, const u16* __restrict__ Kg,
                            const u16* __restrict__ Vg,  // f16, [bh][d][s]
                            const float* __restrict__ mask, float* __restrict__ out, float inv_s) {
    __shared__ u16 Ks[2][64 * 64];
    __shared__ u16 Vt[2][64 * 64];   // [d][kv], swizzled content

    const int tid  = threadIdx.x;
    const int lane = tid & 63;
    const int wid  = tid >> 6;
    const int bh = blockIdx.y;
    const int b = bh / NHEADS;
    const int h = bh % NHEADS;
    const int q0 = blockIdx.x * 64 + wid * 16;
    const int l15 = lane & 15, lh = lane >> 4;

    // staging: linear LDS dest, inverse-swizzled global source
    size_t kSrc[2], vSrc[2]; int ldsOff[2];
    #pragma unroll
    for (int j = 0; j < 2; ++j) {
        int L = wid * 512 + j * 2048 + lane * 8;
        int row = L >> 6;
        int col = (L & 63) ^ ((row & 7) << 3);
        kSrc[j] = (((size_t)bh * SEQ + row) << 6) + col;    // + t*4096 per tile
        vSrc[j] = (((size_t)bh * 64 + row) << 11) + col;    // + t*64 per tile
        ldsOff[j] = wid * 512 + j * 2048;
    }

    // Q fragment (B-operand): lane holds Q[q0+l15][kk*32 + lh*8 .. +7]
    s16x8 qf[2];
    #pragma unroll
    for (int kk = 0; kk < 2; ++kk)
        qf[kk] = *(const s16x8*)(&Qg[(((size_t)bh * SEQ + q0 + l15) << 6) + kk * 32 + lh * 8]);

    f32x4 oacc[4] = {};           // O^T frags: oacc[nd][j] = O[q=l15][d=nd*16+lh*4+j]
    float mrun = -1e30f, lrun = 0.f;

    // prologue: stage tile 0 -> buffer 0
    #pragma unroll
    for (int j = 0; j < 2; ++j) {
        GLOAD_LDS16(&Kg[kSrc[j]], &Ks[0][ldsOff[j]]);
        GLOAD_LDS16(&Vg[vSrc[j]], &Vt[0][ldsOff[j]]);
    }

    const int NT = SEQ / 64;
    for (int t = 0; t < NT; ++t) {
        const int cur = t & 1;
        __syncthreads();  // drains in-flight gload_lds (buf[cur] ready); orders prior reads of buf[cur^1]
        if (t + 1 < NT) {
            #pragma unroll
            for (int j = 0; j < 2; ++j) {
                GLOAD_LDS16(&Kg[kSrc[j] + ((size_t)(t + 1) << 12)], &Ks[cur ^ 1][ldsOff[j]]);
                GLOAD_LDS16(&Vg[vSrc[j] + (size_t)(t + 1) * 64],    &Vt[cur ^ 1][ldsOff[j]]);
            }
        }

        // S^T = mfma(K, Q): sacc[n][j] = S[q=q0+l15][kv = t*64 + n*16 + lh*4 + j]
        f32x4 sacc[4] = {};
        #pragma unroll
        for (int kk = 0; kk < 2; ++kk) {
            #pragma unroll
            for (int n = 0; n < 4; ++n) {
                s16x8 kf = *(const s16x8*)(&Ks[cur][SWZ(n * 16 + l15, kk * 32 + lh * 8)]);
                sacc[n] = __builtin_amdgcn_mfma_f32_16x16x32_bf16(kf, qf[kk], sacc[n], 0, 0, 0);
            }
        }
        #pragma unroll
        for (int n = 0; n < 4; ++n) {
            float4 mv = *(const float4*)(&mask[(size_t)b * SEQ + t * 64 + n * 16 + lh * 4]);
            sacc[n][0] = sacc[n][0] * inv_s + mv.x;
            sacc[n][1] = sacc[n][1] * inv_s + mv.y;
            sacc[n][2] = sacc[n][2] * inv_s + mv.z;
            sacc[n][3] = sacc[n][3] * inv_s + mv.w;
        }

        // per-lane online softmax over this lane's 16 kv values (+2 shuffles across lh groups)
        float tmax = sacc[0][0];
        #pragma unroll
        for (int n = 0; n < 4; ++n)
            #pragma unroll
            for (int j = 0; j < 4; ++j)
                tmax = fmaxf(tmax, sacc[n][j]);
        tmax = fmaxf(tmax, __shfl_xor(tmax, 16));
        tmax = fmaxf(tmax, __shfl_xor(tmax, 32));

        if (!__all(tmax - mrun <= 8.0f)) {   // defer-max: rescale only on real growth
            float mnew = fmaxf(mrun, tmax);
            float alpha = __expf(mrun - mnew);
            lrun *= alpha;
            #pragma unroll
            for (int nd = 0; nd < 4; ++nd)
                #pragma unroll
                for (int j = 0; j < 4; ++j)
                    oacc[nd][j] *= alpha;
            mrun = mnew;
        }

        float rs = 0.f;
        f16x4 pf[4];   // B-frag for 16x16x16: k = lh*4 + e  == S^T D-layout. No shuffles.
        #pragma unroll
        for (int n = 0; n < 4; ++n) {
            #pragma unroll
            for (int j = 0; j < 4; ++j) {
                float p = __expf(sacc[n][j] - mrun);
                rs += p;
                pf[n][j] = (_Float16)p;
            }
        }
        rs += __shfl_xor(rs, 16);
        rs += __shfl_xor(rs, 32);
        lrun += rs;

        // PV: O^T[d][q] += V^T[d][kv] * P^T[kv][q], 16 x mfma_f32_16x16x16f16
        #pragma unroll
        for (int n = 0; n < 4; ++n) {
            #pragma unroll
            for (int nd = 0; nd < 4; ++nd) {
                f16x4 vf = *(const f16x4*)(&Vt[cur][SWZ(nd * 16 + l15, n * 16 + lh * 4)]);
                oacc[nd] = __builtin_amdgcn_mfma_f32_16x16x16f16(vf, pf[n], oacc[nd], 0, 0, 0);
            }
        }
    }

    const float inv = 1.0f / lrun;
    const int s = q0 + l15;
    #pragma unroll
    for (int nd = 0; nd < 4; ++nd) {
        float4 o;
        o.x = oacc[nd][0] * inv;
        o.y = oacc[nd][1] * inv;
        o.z = oacc[nd][2] * inv;
        o.w = oacc[nd][3] * inv;
        *(float4*)(&out[(size_t)(b * SEQ + s) * (NHEADS * 64) + h * 64 + nd * 16 + lh * 4]) = o;
    }
}

extern "C" void kernel_launch(void* const* d_in, const int* in_sizes, int n_in,
                              void* d_out, int out_size, void* d_ws, size_t ws_size,
                              hipStream_t stream) {
    const float* hidden  = (const float*)d_in[0];
    const float* context = (const float*)d_in[1];
    const float* mask    = (const float*)d_in[2];
    const float* Wq = (const float*)d_in[3];
    const float* bq = (const float*)d_in[4];
    const float* Wk = (const float*)d_in[5];
    const float* bk = (const float*)d_in[6];
    const float* Wv = (const float*)d_in[7];
    const float* bv = (const float*)d_in[8];
    float* out = (float*)d_out;

    char* ws = (char*)d_ws;
    const size_t XSZ = (size_t)4096 * 768 * 2;  // activations / per-tensor QKV, bytes
    const size_t WSZ = (size_t)768 * 768 * 2;   // one weight, bytes
    u16* X16  = (u16*)(ws);
    u16* C16  = (u16*)(ws + XSZ);
    u16* W16q = (u16*)(ws + 2 * XSZ);
    u16* W16k = (u16*)(ws + 2 * XSZ + WSZ);
    u16* W16v = (u16*)(ws + 2 * XSZ + 2 * WSZ);
    u16* Q16  = (u16*)(ws + 2 * XSZ + 3 * WSZ);
    u16* K16  = (u16*)(ws + 3 * XSZ + 3 * WSZ);
    u16* V16  = (u16*)(ws + 4 * XSZ + 3 * WSZ);  // f16, transposed [bh][d][s]

    const int n4x = 4096 * 768 / 4;
    const int n4w = 768 * 768 / 4;
    cvt5_kernel<<<dim3((n4x + 255) / 256, 1, 5), 256, 0, stream>>>(
        hidden, context, Wq, Wk, Wv, X16, C16, W16q, W16k, W16v, n4x, n4w);

    qkv_gemm<<<dim3(4096 / 128, 768 / 128, 3), 256, 0, stream>>>(
        X16, C16, W16q, W16k, W16v, bq, bk, bv, Q16, K16, V16);

    float inv_s = (float)(1.0 / sqrt(64.0 + 1e-5));
    attn_kernel<<<dim3(SEQ / 64, NBH), 256, 0, stream>>>(Q16, K16, V16, mask, out, inv_s);
}

// Round 6
// 109.023 us; speedup vs baseline: 1.9481x; 1.0826x over previous
//
#include <hip/hip_runtime.h>
#include <hip/hip_bf16.h>
#include <math.h>

typedef short s16x8 __attribute__((ext_vector_type(8)));
typedef float f32x4 __attribute__((ext_vector_type(4)));
typedef _Float16 f16x4 __attribute__((ext_vector_type(4)));
typedef __fp16 fp16x2 __attribute__((ext_vector_type(2)));
typedef unsigned short u16;

#define NHEADS 12
#define SEQ 2048
#define NBH 24          // B*H
#define KDIM 768
#define LOG2E 1.44269504088896f

// XOR swizzle for u16 tiles with 64-u16 (128 B) rows, 8-u16 (16 B) granularity.
#define SWZ(row, col) (((row) * 64) + ((col) ^ (((row) & 7) << 3)))

// global -> LDS direct, 16B per lane. LDS dest = wave-uniform base + lane*16.
#define GLOAD_LDS16(g, l) __builtin_amdgcn_global_load_lds( \
    (const __attribute__((address_space(1))) unsigned int*)(g), \
    (__attribute__((address_space(3))) unsigned int*)(l), 16, 0, 0)

static __device__ __forceinline__ u16 f2bf(float f) {
    union { float f; unsigned u; } v; v.f = f;
    unsigned r = v.u + 0x7fffu + ((v.u >> 16) & 1u);
    return (u16)(r >> 16);
}
static __device__ __forceinline__ u16 f2h(float f) {
    union { _Float16 h; u16 u; } v; v.h = (_Float16)f;
    return v.u;
}
static __device__ __forceinline__ f16x4 pack4(float a, float b, float c, float d) {
    union { fp16x2 h2[2]; f16x4 h4; } u;
    u.h2[0] = __builtin_amdgcn_cvt_pkrtz(a, b);
    u.h2[1] = __builtin_amdgcn_cvt_pkrtz(c, d);
    return u.h4;
}

// ---------------- f32 -> bf16 convert (z selects tensor; z=2 scales Wq; z=5 mask*log2e f32) ----
__global__ void cvt6_kernel(const float* __restrict__ s0, const float* __restrict__ s1,
                            const float* __restrict__ s2, const float* __restrict__ s3,
                            const float* __restrict__ s4, const float* __restrict__ s5,
                            u16* __restrict__ d0, u16* __restrict__ d1, u16* __restrict__ d2,
                            u16* __restrict__ d3, u16* __restrict__ d4, float* __restrict__ d5,
                            int n4a, int n4w, float qscl) {
    const int z = blockIdx.z;
    int i = blockIdx.x * blockDim.x + threadIdx.x;
    if (z == 5) {
        if (i < (2 * SEQ) / 4) {
            float4 f = ((const float4*)s5)[i];
            f.x *= LOG2E; f.y *= LOG2E; f.z *= LOG2E; f.w *= LOG2E;
            ((float4*)d5)[i] = f;
        }
        return;
    }
    const float* src = (z == 0) ? s0 : (z == 1) ? s1 : (z == 2) ? s2 : (z == 3) ? s3 : s4;
    u16* dst         = (z == 0) ? d0 : (z == 1) ? d1 : (z == 2) ? d2 : (z == 3) ? d3 : d4;
    const int n4     = (z < 2) ? n4a : n4w;
    const float scl  = (z == 2) ? qscl : 1.0f;
    if (i < n4) {
        float4 f = ((const float4*)src)[i];
        ushort4 o;
        o.x = f2bf(f.x * scl); o.y = f2bf(f.y * scl); o.z = f2bf(f.z * scl); o.w = f2bf(f.w * scl);
        ((ushort4*)dst)[i] = o;
    }
}

// ---------------- QKV projection GEMM (double-buffered, 1 barrier/K-step) ----------------
// Q,K out: [bh][s][d] bf16 (Q pre-scaled by inv_s*log2e via Wq/bq).
// V out: TRANSPOSED+pi-PERMUTED [bh][d][s'] f16, s' = s with bits[5:4]<->[3:2] swapped.
__launch_bounds__(256)
__global__ void qkv_gemm(const u16* __restrict__ X, const u16* __restrict__ C,
                         const u16* __restrict__ W0, const u16* __restrict__ W1, const u16* __restrict__ W2,
                         const float* __restrict__ b0, const float* __restrict__ b1, const float* __restrict__ b2,
                         u16* __restrict__ Qo, u16* __restrict__ Ko, u16* __restrict__ Vo, float qscl) {
    const int z = blockIdx.z;
    const u16* A    = (z == 0) ? X  : C;
    const u16* W    = (z == 0) ? W0 : (z == 1) ? W1 : W2;
    const float* bi = (z == 0) ? b0 : (z == 1) ? b1 : b2;
    u16* out        = (z == 0) ? Qo : (z == 1) ? Ko : Vo;
    const float bscl = (z == 0) ? qscl : 1.0f;

    __shared__ u16 As[2][128 * 64];
    __shared__ u16 Bs[2][128 * 64];

    const int tid  = threadIdx.x;
    const int lane = tid & 63;
    const int wid  = tid >> 6;
    const int wr = wid >> 1, wc = wid & 1;
    const int l15 = lane & 15, lh = lane >> 4;
    const int mBase = blockIdx.x * 128;
    const int nBase = blockIdx.y * 128;

    size_t aSrc[4], bSrc[4]; int ldsOffG[4];
    #pragma unroll
    for (int i = 0; i < 4; ++i) {
        int L = wid * 512 + i * 2048 + lane * 8;
        int row = L >> 6;
        int col = (L & 63) ^ ((row & 7) << 3);
        aSrc[i] = (size_t)(mBase + row) * KDIM + col;
        bSrc[i] = (size_t)(nBase + row) * KDIM + col;
        ldsOffG[i] = wid * 512 + i * 2048;
    }

    f32x4 acc[4][4] = {};

    // prologue: stage K-step 0 into buffer 0
    #pragma unroll
    for (int i = 0; i < 4; ++i) {
        GLOAD_LDS16(&A[aSrc[i]], &As[0][ldsOffG[i]]);
        GLOAD_LDS16(&W[bSrc[i]], &Bs[0][ldsOffG[i]]);
    }

    const int NIT = KDIM / 64;
    for (int it = 0; it < NIT; ++it) {
        const int cur = it & 1;
        __syncthreads();  // drains gload_lds: buf[cur] ready
        if (it + 1 < NIT) {
            const int kb = (it + 1) * 64;
            #pragma unroll
            for (int i = 0; i < 4; ++i) {
                GLOAD_LDS16(&A[aSrc[i] + kb], &As[cur ^ 1][ldsOffG[i]]);
                GLOAD_LDS16(&W[bSrc[i] + kb], &Bs[cur ^ 1][ldsOffG[i]]);
            }
        }
        #pragma unroll
        for (int kk = 0; kk < 2; ++kk) {
            s16x8 af[4], bf[4];
            #pragma unroll
            for (int m = 0; m < 4; ++m)
                af[m] = *(const s16x8*)(&As[cur][SWZ(wr * 64 + m * 16 + l15, kk * 32 + lh * 8)]);
            #pragma unroll
            for (int n = 0; n < 4; ++n)
                bf[n] = *(const s16x8*)(&Bs[cur][SWZ(wc * 64 + n * 16 + l15, kk * 32 + lh * 8)]);
            #pragma unroll
            for (int m = 0; m < 4; ++m)
                #pragma unroll
                for (int n = 0; n < 4; ++n)
                    acc[m][n] = __builtin_amdgcn_mfma_f32_16x16x32_bf16(af[m], bf[n], acc[m][n], 0, 0, 0);
        }
    }

    if (z < 2) {
        #pragma unroll
        for (int m = 0; m < 4; ++m) {
            #pragma unroll
            for (int n = 0; n < 4; ++n) {
                int colg = nBase + wc * 64 + n * 16 + l15;
                float bv = bi[colg] * bscl;
                int h = colg >> 6, d = colg & 63;
                #pragma unroll
                for (int j = 0; j < 4; ++j) {
                    int rowg = mBase + wr * 64 + m * 16 + lh * 4 + j;
                    int b = rowg >> 11, s = rowg & 2047;
                    out[(((size_t)(b * NHEADS + h) * SEQ + s) << 6) + d] = f2bf(acc[m][n][j] + bv);
                }
            }
        }
    } else {
        // V: [bh][d][s'] f16, s' = pi(s) (swap kv bit-fields [5:4]<->[3:2]); 4 consecutive s -> ushort4.
        #pragma unroll
        for (int m = 0; m < 4; ++m) {
            #pragma unroll
            for (int n = 0; n < 4; ++n) {
                int colg = nBase + wc * 64 + n * 16 + l15;
                float bv = bi[colg];
                int h = colg >> 6, d = colg & 63;
                int rowg0 = mBase + wr * 64 + m * 16 + lh * 4;
                int b = rowg0 >> 11, s = rowg0 & 2047;
                int sp = (s & ~0x3C) | (((s >> 2) & 3) << 4) | (((s >> 4) & 3) << 2);
                ushort4 o;
                o.x = f2h(acc[m][n][0] + bv);
                o.y = f2h(acc[m][n][1] + bv);
                o.z = f2h(acc[m][n][2] + bv);
                o.w = f2h(acc[m][n][3] + bv);
                *(ushort4*)(&out[(((size_t)(b * NHEADS + h) * 64 + d) << 11) + sp]) = o;
            }
        }
    }
}

// ---------------- flash attention (swapped-QK^T, register softmax, exp2 domain) ----------------
// grid: (SEQ/64, NBH, SPLIT?2:1). 4 waves x 16 q-rows (q = lane&15). KV tile = 64, dbuf,
// one barrier per tile. Vg is f16 [bh][d][s'] pi-permuted -> PV reads are 16B, conflict-free.
template<bool SPLIT>
__launch_bounds__(256)
__global__ void attn_kernel(const u16* __restrict__ Qg, const u16* __restrict__ Kg,
                            const u16* __restrict__ Vg,
                            const float* __restrict__ maskL, float* __restrict__ out,
                            float* __restrict__ Opart, float* __restrict__ MLpart) {
    __shared__ u16 Ks[2][64 * 64];
    __shared__ u16 Vt[2][64 * 64];

    const int tid  = threadIdx.x;
    const int lane = tid & 63;
    const int wid  = tid >> 6;
    const int bh = blockIdx.y;
    const int b = bh / NHEADS;
    const int h = bh % NHEADS;
    const int q0 = blockIdx.x * 64 + wid * 16;
    const int l15 = lane & 15, lh = lane >> 4;
    const int z = SPLIT ? blockIdx.z : 0;
    const int NT = SPLIT ? (SEQ / 128) : (SEQ / 64);
    const int tile0 = z * NT;

    size_t kSrc[2], vSrc[2]; int ldsOff[2];
    #pragma unroll
    for (int j = 0; j < 2; ++j) {
        int L = wid * 512 + j * 2048 + lane * 8;
        int row = L >> 6;
        int col = (L & 63) ^ ((row & 7) << 3);
        kSrc[j] = (((size_t)bh * SEQ + row) << 6) + col + ((size_t)tile0 << 12);
        vSrc[j] = (((size_t)bh * 64 + row) << 11) + col + (size_t)tile0 * 64;
        ldsOff[j] = wid * 512 + j * 2048;
    }

    s16x8 qf[2];
    #pragma unroll
    for (int kk = 0; kk < 2; ++kk)
        qf[kk] = *(const s16x8*)(&Qg[(((size_t)bh * SEQ + q0 + l15) << 6) + kk * 32 + lh * 8]);

    f32x4 oacc[4] = {};           // O^T frags: oacc[nd][j] = O[q=l15][d=nd*16+lh*4+j]
    float mrun = -1e30f, lrun = 0.f;   // log2-domain running max / denom

    #pragma unroll
    for (int j = 0; j < 2; ++j) {
        GLOAD_LDS16(&Kg[kSrc[j]], &Ks[0][ldsOff[j]]);
        GLOAD_LDS16(&Vg[vSrc[j]], &Vt[0][ldsOff[j]]);
    }

    for (int t = 0; t < NT; ++t) {
        const int cur = t & 1;
        __syncthreads();
        if (t + 1 < NT) {
            #pragma unroll
            for (int j = 0; j < 2; ++j) {
                GLOAD_LDS16(&Kg[kSrc[j] + ((size_t)(t + 1) << 12)], &Ks[cur ^ 1][ldsOff[j]]);
                GLOAD_LDS16(&Vg[vSrc[j] + (size_t)(t + 1) * 64],    &Vt[cur ^ 1][ldsOff[j]]);
            }
        }

        // S^T = mfma(K, Q): sacc[n][j] = S2[q=q0+l15][kv=(tile0+t)*64 + n*16 + lh*4 + j]
        f32x4 sacc[4] = {};
        __builtin_amdgcn_s_setprio(1);
        #pragma unroll
        for (int kk = 0; kk < 2; ++kk) {
            #pragma unroll
            for (int n = 0; n < 4; ++n) {
                s16x8 kf = *(const s16x8*)(&Ks[cur][SWZ(n * 16 + l15, kk * 32 + lh * 8)]);
                sacc[n] = __builtin_amdgcn_mfma_f32_16x16x32_bf16(kf, qf[kk], sacc[n], 0, 0, 0);
            }
        }
        __builtin_amdgcn_s_setprio(0);
        #pragma unroll
        for (int n = 0; n < 4; ++n) {
            float4 mv = *(const float4*)(&maskL[(size_t)b * SEQ + (tile0 + t) * 64 + n * 16 + lh * 4]);
            sacc[n][0] += mv.x; sacc[n][1] += mv.y; sacc[n][2] += mv.z; sacc[n][3] += mv.w;
        }

        float tmax = sacc[0][0];
        #pragma unroll
        for (int n = 0; n < 4; ++n)
            #pragma unroll
            for (int j = 0; j < 4; ++j)
                tmax = fmaxf(tmax, sacc[n][j]);
        tmax = fmaxf(tmax, __shfl_xor(tmax, 16));
        tmax = fmaxf(tmax, __shfl_xor(tmax, 32));

        if (!__all(tmax - mrun <= 11.0f)) {   // defer-max (log2 domain)
            float mnew = fmaxf(mrun, tmax);
            float alpha = __builtin_amdgcn_exp2f(mrun - mnew);
            lrun *= alpha;
            #pragma unroll
            for (int nd = 0; nd < 4; ++nd)
                #pragma unroll
                for (int j = 0; j < 4; ++j)
                    oacc[nd][j] *= alpha;
            mrun = mnew;
        }

        float rs = 0.f;
        f16x4 pf[4];   // B-frag (16x16x16): k = lh*4 + e == S^T D-layout
        #pragma unroll
        for (int n = 0; n < 4; ++n) {
            float p0 = __builtin_amdgcn_exp2f(sacc[n][0] - mrun);
            float p1 = __builtin_amdgcn_exp2f(sacc[n][1] - mrun);
            float p2 = __builtin_amdgcn_exp2f(sacc[n][2] - mrun);
            float p3 = __builtin_amdgcn_exp2f(sacc[n][3] - mrun);
            rs += (p0 + p1) + (p2 + p3);
            pf[n] = pack4(p0, p1, p2, p3);
        }
        rs += __shfl_xor(rs, 16);
        rs += __shfl_xor(rs, 32);
        lrun += rs;

        // PV: one 16B read covers frags n=2kk,2kk+1 (pi-permuted V layout)
        __builtin_amdgcn_s_setprio(1);
        #pragma unroll
        for (int kk = 0; kk < 2; ++kk) {
            #pragma unroll
            for (int nd = 0; nd < 4; ++nd) {
                s16x8 v2 = *(const s16x8*)(&Vt[cur][SWZ(nd * 16 + l15, lh * 16 + kk * 8)]);
                union { s16x8 s8; f16x4 h4[2]; } u; u.s8 = v2;
                oacc[nd] = __builtin_amdgcn_mfma_f32_16x16x16f16(u.h4[0], pf[2 * kk],     oacc[nd], 0, 0, 0);
                oacc[nd] = __builtin_amdgcn_mfma_f32_16x16x16f16(u.h4[1], pf[2 * kk + 1], oacc[nd], 0, 0, 0);
            }
        }
        __builtin_amdgcn_s_setprio(0);
    }

    const float inv = 1.0f / lrun;
    const int s = q0 + l15;
    if (!SPLIT) {
        #pragma unroll
        for (int nd = 0; nd < 4; ++nd) {
            float4 o;
            o.x = oacc[nd][0] * inv; o.y = oacc[nd][1] * inv;
            o.z = oacc[nd][2] * inv; o.w = oacc[nd][3] * inv;
            *(float4*)(&out[(size_t)(b * SEQ + s) * (NHEADS * 64) + h * 64 + nd * 16 + lh * 4]) = o;
        }
    } else {
        const size_t rbase = ((size_t)(z * NBH + bh) * SEQ + s);
        #pragma unroll
        for (int nd = 0; nd < 4; ++nd) {
            float4 o;
            o.x = oacc[nd][0] * inv; o.y = oacc[nd][1] * inv;
            o.z = oacc[nd][2] * inv; o.w = oacc[nd][3] * inv;
            *(float4*)(&Opart[rbase * 64 + nd * 16 + lh * 4]) = o;
        }
        if (lh == 0)
            *(float2*)(&MLpart[rbase * 2]) = make_float2(mrun, lrun);
    }
}

// ---------------- split-KV combine ----------------
__global__ void combine_kernel(const float* __restrict__ Opart, const float* __restrict__ MLpart,
                               float* __restrict__ out) {
    int gid = blockIdx.x * 256 + threadIdx.x;   // NBH*SEQ*16 = 786432 threads
    int row = gid >> 4, d4 = gid & 15;
    float2 ml0 = ((const float2*)MLpart)[row];
    float2 ml1 = ((const float2*)MLpart)[NBH * SEQ + row];
    float m = fmaxf(ml0.x, ml1.x);
    float w0 = __builtin_amdgcn_exp2f(ml0.x - m) * ml0.y;
    float w1 = __builtin_amdgcn_exp2f(ml1.x - m) * ml1.y;
    float inv = 1.0f / (w0 + w1);
    w0 *= inv; w1 *= inv;
    float4 o0 = *(const float4*)(&Opart[(size_t)row * 64 + d4 * 4]);
    float4 o1 = *(const float4*)(&Opart[(size_t)NBH * SEQ * 64 + (size_t)row * 64 + d4 * 4]);
    float4 o;
    o.x = o0.x * w0 + o1.x * w1; o.y = o0.y * w0 + o1.y * w1;
    o.z = o0.z * w0 + o1.z * w1; o.w = o0.w * w0 + o1.w * w1;
    int bh = row >> 11, s = row & 2047;
    int b = bh / NHEADS, hh = bh % NHEADS;
    *(float4*)(&out[(size_t)(b * SEQ + s) * (NHEADS * 64) + hh * 64 + d4 * 4]) = o;
}

extern "C" void kernel_launch(void* const* d_in, const int* in_sizes, int n_in,
                              void* d_out, int out_size, void* d_ws, size_t ws_size,
                              hipStream_t stream) {
    const float* hidden  = (const float*)d_in[0];
    const float* context = (const float*)d_in[1];
    const float* mask    = (const float*)d_in[2];
    const float* Wq = (const float*)d_in[3];
    const float* bq = (const float*)d_in[4];
    const float* Wk = (const float*)d_in[5];
    const float* bk = (const float*)d_in[6];
    const float* Wv = (const float*)d_in[7];
    const float* bv = (const float*)d_in[8];
    float* out = (float*)d_out;

    char* ws = (char*)d_ws;
    const size_t XSZ = (size_t)4096 * 768 * 2;
    const size_t WSZ = (size_t)768 * 768 * 2;
    u16* X16  = (u16*)(ws);
    u16* C16  = (u16*)(ws + XSZ);
    u16* W16q = (u16*)(ws + 2 * XSZ);
    u16* W16k = (u16*)(ws + 2 * XSZ + WSZ);
    u16* W16v = (u16*)(ws + 2 * XSZ + 2 * WSZ);
    u16* Q16  = (u16*)(ws + 2 * XSZ + 3 * WSZ);
    u16* K16  = (u16*)(ws + 3 * XSZ + 3 * WSZ);
    u16* V16  = (u16*)(ws + 4 * XSZ + 3 * WSZ);    // f16, [bh][d][s'] pi-permuted
    const size_t MASKL_OFF = 5 * XSZ + 3 * WSZ;    // 34,996,224
    float* maskL = (float*)(ws + MASKL_OFF);
    const size_t OPART_OFF = MASKL_OFF + 2 * SEQ * sizeof(float) + 256;
    float* Opart = (float*)(ws + OPART_OFF);                        // 25.2 MB
    const size_t ML_OFF = OPART_OFF + (size_t)2 * NBH * SEQ * 64 * 4;
    float* MLpart = (float*)(ws + ML_OFF);                          // 786 KB
    const size_t WS_NEED_SPLIT = ML_OFF + (size_t)2 * NBH * SEQ * 2 * 4;

    const float qscl = (float)((1.0 / sqrt(64.0 + 1e-5)) * 1.44269504088896);

    const int n4x = 4096 * 768 / 4;
    const int n4w = 768 * 768 / 4;
    cvt6_kernel<<<dim3((n4x + 255) / 256, 1, 6), 256, 0, stream>>>(
        hidden, context, Wq, Wk, Wv, mask,
        X16, C16, W16q, W16k, W16v, maskL, n4x, n4w, qscl);

    qkv_gemm<<<dim3(4096 / 128, 768 / 128, 3), 256, 0, stream>>>(
        X16, C16, W16q, W16k, W16v, bq, bk, bv, Q16, K16, V16, qscl);

    if (ws_size >= WS_NEED_SPLIT) {
        attn_kernel<true><<<dim3(SEQ / 64, NBH, 2), 256, 0, stream>>>(
            Q16, K16, V16, maskL, out, Opart, MLpart);
        combine_kernel<<<(NBH * SEQ * 16) / 256, 256, 0, stream>>>(Opart, MLpart, out);
    } else {
        attn_kernel<false><<<dim3(SEQ / 64, NBH, 1), 256, 0, stream>>>(
            Q16, K16, V16, maskL, out, Opart, MLpart);
    }
}

// Round 7
// 98.791 us; speedup vs baseline: 2.1499x; 1.1036x over previous
//
#include <hip/hip_runtime.h>
#include <hip/hip_bf16.h>
#include <math.h>

typedef short s16x8 __attribute__((ext_vector_type(8)));
typedef float f32x4 __attribute__((ext_vector_type(4)));
typedef _Float16 f16x4 __attribute__((ext_vector_type(4)));
typedef __fp16 fp16x2 __attribute__((ext_vector_type(2)));
typedef unsigned short u16;

#define NHEADS 12
#define SEQ 2048
#define NBH 24          // B*H
#define KDIM 768
#define LOG2E 1.44269504088896f

// XOR swizzle for u16 tiles with 64-u16 (128 B) rows, 8-u16 (16 B) granularity.
#define SWZ(row, col) (((row) * 64) + ((col) ^ (((row) & 7) << 3)))

// global -> LDS direct, 16B per lane. LDS dest = wave-uniform base + lane*16.
#define GLOAD_LDS16(g, l) __builtin_amdgcn_global_load_lds( \
    (const __attribute__((address_space(1))) unsigned int*)(g), \
    (__attribute__((address_space(3))) unsigned int*)(l), 16, 0, 0)

static __device__ __forceinline__ u16 f2bf(float f) {
    union { float f; unsigned u; } v; v.f = f;
    unsigned r = v.u + 0x7fffu + ((v.u >> 16) & 1u);
    return (u16)(r >> 16);
}
static __device__ __forceinline__ u16 f2h(float f) {
    union { _Float16 h; u16 u; } v; v.h = (_Float16)f;
    return v.u;
}
static __device__ __forceinline__ f16x4 pack4(float a, float b, float c, float d) {
    union { fp16x2 h2[2]; f16x4 h4; } u;
    u.h2[0] = __builtin_amdgcn_cvt_pkrtz(a, b);
    u.h2[1] = __builtin_amdgcn_cvt_pkrtz(c, d);
    return u.h4;
}

// ---------------- f32 -> bf16 convert (z selects tensor; z=2 scales Wq; z=5 mask*log2e f32) ----
__global__ void cvt6_kernel(const float* __restrict__ s0, const float* __restrict__ s1,
                            const float* __restrict__ s2, const float* __restrict__ s3,
                            const float* __restrict__ s4, const float* __restrict__ s5,
                            u16* __restrict__ d0, u16* __restrict__ d1, u16* __restrict__ d2,
                            u16* __restrict__ d3, u16* __restrict__ d4, float* __restrict__ d5,
                            int n4a, int n4w, float qscl) {
    const int z = blockIdx.z;
    int i = blockIdx.x * blockDim.x + threadIdx.x;
    if (z == 5) {
        if (i < (2 * SEQ) / 4) {
            float4 f = ((const float4*)s5)[i];
            f.x *= LOG2E; f.y *= LOG2E; f.z *= LOG2E; f.w *= LOG2E;
            ((float4*)d5)[i] = f;
        }
        return;
    }
    const float* src = (z == 0) ? s0 : (z == 1) ? s1 : (z == 2) ? s2 : (z == 3) ? s3 : s4;
    u16* dst         = (z == 0) ? d0 : (z == 1) ? d1 : (z == 2) ? d2 : (z == 3) ? d3 : d4;
    const int n4     = (z < 2) ? n4a : n4w;
    const float scl  = (z == 2) ? qscl : 1.0f;
    if (i < n4) {
        float4 f = ((const float4*)src)[i];
        ushort4 o;
        o.x = f2bf(f.x * scl); o.y = f2bf(f.y * scl); o.z = f2bf(f.z * scl); o.w = f2bf(f.w * scl);
        ((ushort4*)dst)[i] = o;
    }
}

// ---------------- QKV projection GEMM (double-buffered, 1 barrier/K-step) ----------------
// Q,K out: [bh][s][d] bf16 (Q pre-scaled by inv_s*log2e via Wq/bq).
// V out: TRANSPOSED+pi-PERMUTED [bh][d][s'] f16, s' = s with bits[5:4]<->[3:2] swapped.
__launch_bounds__(256)
__global__ void qkv_gemm(const u16* __restrict__ X, const u16* __restrict__ C,
                         const u16* __restrict__ W0, const u16* __restrict__ W1, const u16* __restrict__ W2,
                         const float* __restrict__ b0, const float* __restrict__ b1, const float* __restrict__ b2,
                         u16* __restrict__ Qo, u16* __restrict__ Ko, u16* __restrict__ Vo, float qscl) {
    const int z = blockIdx.z;
    const u16* A    = (z == 0) ? X  : C;
    const u16* W    = (z == 0) ? W0 : (z == 1) ? W1 : W2;
    const float* bi = (z == 0) ? b0 : (z == 1) ? b1 : b2;
    u16* out        = (z == 0) ? Qo : (z == 1) ? Ko : Vo;
    const float bscl = (z == 0) ? qscl : 1.0f;

    __shared__ u16 As[2][128 * 64];
    __shared__ u16 Bs[2][128 * 64];

    const int tid  = threadIdx.x;
    const int lane = tid & 63;
    const int wid  = tid >> 6;
    const int wr = wid >> 1, wc = wid & 1;
    const int l15 = lane & 15, lh = lane >> 4;
    const int mBase = blockIdx.x * 128;
    const int nBase = blockIdx.y * 128;

    size_t aSrc[4], bSrc[4]; int ldsOffG[4];
    #pragma unroll
    for (int i = 0; i < 4; ++i) {
        int L = wid * 512 + i * 2048 + lane * 8;
        int row = L >> 6;
        int col = (L & 63) ^ ((row & 7) << 3);
        aSrc[i] = (size_t)(mBase + row) * KDIM + col;
        bSrc[i] = (size_t)(nBase + row) * KDIM + col;
        ldsOffG[i] = wid * 512 + i * 2048;
    }

    f32x4 acc[4][4] = {};

    // prologue: stage K-step 0 into buffer 0
    #pragma unroll
    for (int i = 0; i < 4; ++i) {
        GLOAD_LDS16(&A[aSrc[i]], &As[0][ldsOffG[i]]);
        GLOAD_LDS16(&W[bSrc[i]], &Bs[0][ldsOffG[i]]);
    }

    const int NIT = KDIM / 64;
    for (int it = 0; it < NIT; ++it) {
        const int cur = it & 1;
        __syncthreads();  // drains gload_lds: buf[cur] ready
        if (it + 1 < NIT) {
            const int kb = (it + 1) * 64;
            #pragma unroll
            for (int i = 0; i < 4; ++i) {
                GLOAD_LDS16(&A[aSrc[i] + kb], &As[cur ^ 1][ldsOffG[i]]);
                GLOAD_LDS16(&W[bSrc[i] + kb], &Bs[cur ^ 1][ldsOffG[i]]);
            }
        }
        #pragma unroll
        for (int kk = 0; kk < 2; ++kk) {
            s16x8 af[4], bf[4];
            #pragma unroll
            for (int m = 0; m < 4; ++m)
                af[m] = *(const s16x8*)(&As[cur][SWZ(wr * 64 + m * 16 + l15, kk * 32 + lh * 8)]);
            #pragma unroll
            for (int n = 0; n < 4; ++n)
                bf[n] = *(const s16x8*)(&Bs[cur][SWZ(wc * 64 + n * 16 + l15, kk * 32 + lh * 8)]);
            #pragma unroll
            for (int m = 0; m < 4; ++m)
                #pragma unroll
                for (int n = 0; n < 4; ++n)
                    acc[m][n] = __builtin_amdgcn_mfma_f32_16x16x32_bf16(af[m], bf[n], acc[m][n], 0, 0, 0);
        }
    }

    if (z < 2) {
        #pragma unroll
        for (int m = 0; m < 4; ++m) {
            #pragma unroll
            for (int n = 0; n < 4; ++n) {
                int colg = nBase + wc * 64 + n * 16 + l15;
                float bv = bi[colg] * bscl;
                int h = colg >> 6, d = colg & 63;
                #pragma unroll
                for (int j = 0; j < 4; ++j) {
                    int rowg = mBase + wr * 64 + m * 16 + lh * 4 + j;
                    int b = rowg >> 11, s = rowg & 2047;
                    out[(((size_t)(b * NHEADS + h) * SEQ + s) << 6) + d] = f2bf(acc[m][n][j] + bv);
                }
            }
        }
    } else {
        // V: [bh][d][s'] f16, s' = pi(s) (swap kv bit-fields [5:4]<->[3:2]); 4 consecutive s -> ushort4.
        #pragma unroll
        for (int m = 0; m < 4; ++m) {
            #pragma unroll
            for (int n = 0; n < 4; ++n) {
                int colg = nBase + wc * 64 + n * 16 + l15;
                float bv = bi[colg];
                int h = colg >> 6, d = colg & 63;
                int rowg0 = mBase + wr * 64 + m * 16 + lh * 4;
                int b = rowg0 >> 11, s = rowg0 & 2047;
                int sp = (s & ~0x3C) | (((s >> 2) & 3) << 4) | (((s >> 4) & 3) << 2);
                ushort4 o;
                o.x = f2h(acc[m][n][0] + bv);
                o.y = f2h(acc[m][n][1] + bv);
                o.z = f2h(acc[m][n][2] + bv);
                o.w = f2h(acc[m][n][3] + bv);
                *(ushort4*)(&out[(((size_t)(b * NHEADS + h) * 64 + d) << 11) + sp]) = o;
            }
        }
    }
}

// ---------------- flash attention (swapped-QK^T, register softmax, exp2 domain) ----------------
// grid: (SEQ/128, NBH, SPLIT?2:1). 8 waves x 16 q-rows (q = lane&15). KV tile = 64, dbuf,
// one barrier per tile. Vg is f16 [bh][d][s'] pi-permuted -> PV reads are 16B.
// 8-wave blocks: 32KB LDS shared by 8 waves -> 3 blocks/CU = 24 waves/CU.
template<bool SPLIT>
__launch_bounds__(512)
__global__ void attn_kernel(const u16* __restrict__ Qg, const u16* __restrict__ Kg,
                            const u16* __restrict__ Vg,
                            const float* __restrict__ maskL, float* __restrict__ out,
                            float* __restrict__ Opart, float* __restrict__ MLpart) {
    __shared__ u16 Ks[2][64 * 64];
    __shared__ u16 Vt[2][64 * 64];

    const int tid  = threadIdx.x;
    const int lane = tid & 63;
    const int wid  = tid >> 6;
    const int bh = blockIdx.y;
    const int b = bh / NHEADS;
    const int h = bh % NHEADS;
    const int q0 = blockIdx.x * 128 + wid * 16;
    const int l15 = lane & 15, lh = lane >> 4;
    const int z = SPLIT ? blockIdx.z : 0;
    const int NT = SPLIT ? (SEQ / 128) : (SEQ / 64);
    const int tile0 = z * NT;

    // staging: 512 threads x 16B = full 64x64 u16 tile in one gload round.
    // linear LDS dest (base wave-uniform), inverse-swizzled global source.
    const int srow = tid >> 3;
    const int scol = ((tid & 7) * 8) ^ ((srow & 7) << 3);
    const size_t kSrc = (((size_t)bh * SEQ + srow) << 6) + scol + ((size_t)tile0 << 12);
    const size_t vSrc = (((size_t)bh * 64 + srow) << 11) + scol + (size_t)tile0 * 64;
    const int ldsBase = wid * 512;   // u16 units; lane*8 added by HW

    s16x8 qf[2];
    #pragma unroll
    for (int kk = 0; kk < 2; ++kk)
        qf[kk] = *(const s16x8*)(&Qg[(((size_t)bh * SEQ + q0 + l15) << 6) + kk * 32 + lh * 8]);

    f32x4 oacc[4] = {};           // O^T frags: oacc[nd][j] = O[q=l15][d=nd*16+lh*4+j]
    float mrun = -1e30f, lrun = 0.f;   // log2-domain running max / denom

    GLOAD_LDS16(&Kg[kSrc], &Ks[0][ldsBase]);
    GLOAD_LDS16(&Vg[vSrc], &Vt[0][ldsBase]);

    for (int t = 0; t < NT; ++t) {
        const int cur = t & 1;
        __syncthreads();
        if (t + 1 < NT) {
            GLOAD_LDS16(&Kg[kSrc + ((size_t)(t + 1) << 12)], &Ks[cur ^ 1][ldsBase]);
            GLOAD_LDS16(&Vg[vSrc + (size_t)(t + 1) * 64],    &Vt[cur ^ 1][ldsBase]);
        }

        // S^T = mfma(K, Q): sacc[n][j] = S2[q=q0+l15][kv=(tile0+t)*64 + n*16 + lh*4 + j]
        f32x4 sacc[4] = {};
        __builtin_amdgcn_s_setprio(1);
        #pragma unroll
        for (int kk = 0; kk < 2; ++kk) {
            #pragma unroll
            for (int n = 0; n < 4; ++n) {
                s16x8 kf = *(const s16x8*)(&Ks[cur][SWZ(n * 16 + l15, kk * 32 + lh * 8)]);
                sacc[n] = __builtin_amdgcn_mfma_f32_16x16x32_bf16(kf, qf[kk], sacc[n], 0, 0, 0);
            }
        }
        __builtin_amdgcn_s_setprio(0);
        #pragma unroll
        for (int n = 0; n < 4; ++n) {
            float4 mv = *(const float4*)(&maskL[(size_t)b * SEQ + (tile0 + t) * 64 + n * 16 + lh * 4]);
            sacc[n][0] += mv.x; sacc[n][1] += mv.y; sacc[n][2] += mv.z; sacc[n][3] += mv.w;
        }

        float tmax = sacc[0][0];
        #pragma unroll
        for (int n = 0; n < 4; ++n)
            #pragma unroll
            for (int j = 0; j < 4; ++j)
                tmax = fmaxf(tmax, sacc[n][j]);
        tmax = fmaxf(tmax, __shfl_xor(tmax, 16));
        tmax = fmaxf(tmax, __shfl_xor(tmax, 32));

        if (!__all(tmax - mrun <= 11.0f)) {   // defer-max (log2 domain)
            float mnew = fmaxf(mrun, tmax);
            float alpha = __builtin_amdgcn_exp2f(mrun - mnew);
            lrun *= alpha;
            #pragma unroll
            for (int nd = 0; nd < 4; ++nd)
                #pragma unroll
                for (int j = 0; j < 4; ++j)
                    oacc[nd][j] *= alpha;
            mrun = mnew;
        }

        float rs = 0.f;
        f16x4 pf[4];   // B-frag (16x16x16): k = lh*4 + e == S^T D-layout
        #pragma unroll
        for (int n = 0; n < 4; ++n) {
            float p0 = __builtin_amdgcn_exp2f(sacc[n][0] - mrun);
            float p1 = __builtin_amdgcn_exp2f(sacc[n][1] - mrun);
            float p2 = __builtin_amdgcn_exp2f(sacc[n][2] - mrun);
            float p3 = __builtin_amdgcn_exp2f(sacc[n][3] - mrun);
            rs += (p0 + p1) + (p2 + p3);
            pf[n] = pack4(p0, p1, p2, p3);
        }
        rs += __shfl_xor(rs, 16);
        rs += __shfl_xor(rs, 32);
        lrun += rs;

        // PV: one 16B read covers frags n=2kk,2kk+1 (pi-permuted V layout)
        __builtin_amdgcn_s_setprio(1);
        #pragma unroll
        for (int kk = 0; kk < 2; ++kk) {
            #pragma unroll
            for (int nd = 0; nd < 4; ++nd) {
                s16x8 v2 = *(const s16x8*)(&Vt[cur][SWZ(nd * 16 + l15, lh * 16 + kk * 8)]);
                union { s16x8 s8; f16x4 h4[2]; } u; u.s8 = v2;
                oacc[nd] = __builtin_amdgcn_mfma_f32_16x16x16f16(u.h4[0], pf[2 * kk],     oacc[nd], 0, 0, 0);
                oacc[nd] = __builtin_amdgcn_mfma_f32_16x16x16f16(u.h4[1], pf[2 * kk + 1], oacc[nd], 0, 0, 0);
            }
        }
        __builtin_amdgcn_s_setprio(0);
    }

    const float inv = 1.0f / lrun;
    const int s = q0 + l15;
    if (!SPLIT) {
        #pragma unroll
        for (int nd = 0; nd < 4; ++nd) {
            float4 o;
            o.x = oacc[nd][0] * inv; o.y = oacc[nd][1] * inv;
            o.z = oacc[nd][2] * inv; o.w = oacc[nd][3] * inv;
            *(float4*)(&out[(size_t)(b * SEQ + s) * (NHEADS * 64) + h * 64 + nd * 16 + lh * 4]) = o;
        }
    } else {
        const size_t rbase = ((size_t)(z * NBH + bh) * SEQ + s);
        #pragma unroll
        for (int nd = 0; nd < 4; ++nd) {
            float4 o;
            o.x = oacc[nd][0] * inv; o.y = oacc[nd][1] * inv;
            o.z = oacc[nd][2] * inv; o.w = oacc[nd][3] * inv;
            *(float4*)(&Opart[rbase * 64 + nd * 16 + lh * 4]) = o;
        }
        if (lh == 0)
            *(float2*)(&MLpart[rbase * 2]) = make_float2(mrun, lrun);
    }
}

// ---------------- split-KV combine ----------------
__global__ void combine_kernel(const float* __restrict__ Opart, const float* __restrict__ MLpart,
                               float* __restrict__ out) {
    int gid = blockIdx.x * 256 + threadIdx.x;   // NBH*SEQ*16 = 786432 threads
    int row = gid >> 4, d4 = gid & 15;
    float2 ml0 = ((const float2*)MLpart)[row];
    float2 ml1 = ((const float2*)MLpart)[NBH * SEQ + row];
    float m = fmaxf(ml0.x, ml1.x);
    float w0 = __builtin_amdgcn_exp2f(ml0.x - m) * ml0.y;
    float w1 = __builtin_amdgcn_exp2f(ml1.x - m) * ml1.y;
    float inv = 1.0f / (w0 + w1);
    w0 *= inv; w1 *= inv;
    float4 o0 = *(const float4*)(&Opart[(size_t)row * 64 + d4 * 4]);
    float4 o1 = *(const float4*)(&Opart[(size_t)NBH * SEQ * 64 + (size_t)row * 64 + d4 * 4]);
    float4 o;
    o.x = o0.x * w0 + o1.x * w1; o.y = o0.y * w0 + o1.y * w1;
    o.z = o0.z * w0 + o1.z * w1; o.w = o0.w * w0 + o1.w * w1;
    int bh = row >> 11, s = row & 2047;
    int b = bh / NHEADS, hh = bh % NHEADS;
    *(float4*)(&out[(size_t)(b * SEQ + s) * (NHEADS * 64) + hh * 64 + d4 * 4]) = o;
}

extern "C" void kernel_launch(void* const* d_in, const int* in_sizes, int n_in,
                              void* d_out, int out_size, void* d_ws, size_t ws_size,
                              hipStream_t stream) {
    const float* hidden  = (const float*)d_in[0];
    const float* context = (const float*)d_in[1];
    const float* mask    = (const float*)d_in[2];
    const float* Wq = (const float*)d_in[3];
    const float* bq = (const float*)d_in[4];
    const float* Wk = (const float*)d_in[5];
    const float* bk = (const float*)d_in[6];
    const float* Wv = (const float*)d_in[7];
    const float* bv = (const float*)d_in[8];
    float* out = (float*)d_out;

    char* ws = (char*)d_ws;
    const size_t XSZ = (size_t)4096 * 768 * 2;
    const size_t WSZ = (size_t)768 * 768 * 2;
    u16* X16  = (u16*)(ws);
    u16* C16  = (u16*)(ws + XSZ);
    u16* W16q = (u16*)(ws + 2 * XSZ);
    u16* W16k = (u16*)(ws + 2 * XSZ + WSZ);
    u16* W16v = (u16*)(ws + 2 * XSZ + 2 * WSZ);
    u16* Q16  = (u16*)(ws + 2 * XSZ + 3 * WSZ);
    u16* K16  = (u16*)(ws + 3 * XSZ + 3 * WSZ);
    u16* V16  = (u16*)(ws + 4 * XSZ + 3 * WSZ);    // f16, [bh][d][s'] pi-permuted
    const size_t MASKL_OFF = 5 * XSZ + 3 * WSZ;    // 34,996,224
    float* maskL = (float*)(ws + MASKL_OFF);
    const size_t OPART_OFF = MASKL_OFF + 2 * SEQ * sizeof(float) + 256;
    float* Opart = (float*)(ws + OPART_OFF);                        // 25.2 MB
    const size_t ML_OFF = OPART_OFF + (size_t)2 * NBH * SEQ * 64 * 4;
    float* MLpart = (float*)(ws + ML_OFF);                          // 786 KB
    const size_t WS_NEED_SPLIT = ML_OFF + (size_t)2 * NBH * SEQ * 2 * 4;

    const float qscl = (float)((1.0 / sqrt(64.0 + 1e-5)) * 1.44269504088896);

    const int n4x = 4096 * 768 / 4;
    const int n4w = 768 * 768 / 4;
    cvt6_kernel<<<dim3((n4x + 255) / 256, 1, 6), 256, 0, stream>>>(
        hidden, context, Wq, Wk, Wv, mask,
        X16, C16, W16q, W16k, W16v, maskL, n4x, n4w, qscl);

    qkv_gemm<<<dim3(4096 / 128, 768 / 128, 3), 256, 0, stream>>>(
        X16, C16, W16q, W16k, W16v, bq, bk, bv, Q16, K16, V16, qscl);

    if (ws_size >= WS_NEED_SPLIT) {
        attn_kernel<true><<<dim3(SEQ / 128, NBH, 2), 512, 0, stream>>>(
            Q16, K16, V16, maskL, out, Opart, MLpart);
        combine_kernel<<<(NBH * SEQ * 16) / 256, 256, 0, stream>>>(Opart, MLpart, out);
    } else {
        attn_kernel<false><<<dim3(SEQ / 128, NBH, 1), 512, 0, stream>>>(
            Q16, K16, V16, maskL, out, Opart, MLpart);
    }
}

// Round 8
// 93.029 us; speedup vs baseline: 2.2831x; 1.0619x over previous
//
#include <hip/hip_runtime.h>
#include <hip/hip_bf16.h>
#include <math.h>

typedef short s16x8 __attribute__((ext_vector_type(8)));
typedef float f32x4 __attribute__((ext_vector_type(4)));
typedef _Float16 f16x4 __attribute__((ext_vector_type(4)));
typedef __fp16 fp16x2 __attribute__((ext_vector_type(2)));
typedef unsigned short u16;

#define NHEADS 12
#define SEQ 2048
#define NBH 24          // B*H
#define KDIM 768
#define LOG2E 1.44269504088896f

// XOR swizzle for u16 tiles with 64-u16 (128 B) rows, 8-u16 (16 B) granularity.
#define SWZ(row, col) (((row) * 64) + ((col) ^ (((row) & 7) << 3)))

// global -> LDS direct, 16B per lane. LDS dest = wave-uniform base + lane*16.
#define GLOAD_LDS16(g, l) __builtin_amdgcn_global_load_lds( \
    (const __attribute__((address_space(1))) unsigned int*)(g), \
    (__attribute__((address_space(3))) unsigned int*)(l), 16, 0, 0)

static __device__ __forceinline__ u16 f2bf(float f) {
    union { float f; unsigned u; } v; v.f = f;
    unsigned r = v.u + 0x7fffu + ((v.u >> 16) & 1u);
    return (u16)(r >> 16);
}
static __device__ __forceinline__ u16 f2h(float f) {
    union { _Float16 h; u16 u; } v; v.h = (_Float16)f;
    return v.u;
}
static __device__ __forceinline__ f16x4 pack4(float a, float b, float c, float d) {
    union { fp16x2 h2[2]; f16x4 h4; } u;
    u.h2[0] = __builtin_amdgcn_cvt_pkrtz(a, b);
    u.h2[1] = __builtin_amdgcn_cvt_pkrtz(c, d);
    return u.h4;
}

// ---------------- f32 -> bf16 convert (z selects tensor; z=2 scales Wq; z=5 mask*log2e f32) ----
__global__ void cvt6_kernel(const float* __restrict__ s0, const float* __restrict__ s1,
                            const float* __restrict__ s2, const float* __restrict__ s3,
                            const float* __restrict__ s4, const float* __restrict__ s5,
                            u16* __restrict__ d0, u16* __restrict__ d1, u16* __restrict__ d2,
                            u16* __restrict__ d3, u16* __restrict__ d4, float* __restrict__ d5,
                            int n4a, int n4w, float qscl) {
    const int z = blockIdx.z;
    int i = blockIdx.x * blockDim.x + threadIdx.x;
    if (z == 5) {
        if (i < (2 * SEQ) / 4) {
            float4 f = ((const float4*)s5)[i];
            f.x *= LOG2E; f.y *= LOG2E; f.z *= LOG2E; f.w *= LOG2E;
            ((float4*)d5)[i] = f;
        }
        return;
    }
    const float* src = (z == 0) ? s0 : (z == 1) ? s1 : (z == 2) ? s2 : (z == 3) ? s3 : s4;
    u16* dst         = (z == 0) ? d0 : (z == 1) ? d1 : (z == 2) ? d2 : (z == 3) ? d3 : d4;
    const int n4     = (z < 2) ? n4a : n4w;
    const float scl  = (z == 2) ? qscl : 1.0f;
    if (i < n4) {
        float4 f = ((const float4*)src)[i];
        ushort4 o;
        o.x = f2bf(f.x * scl); o.y = f2bf(f.y * scl); o.z = f2bf(f.z * scl); o.w = f2bf(f.w * scl);
        ((ushort4*)dst)[i] = o;
    }
}

// ---------------- QKV projection GEMM (double-buffered, 1 barrier/K-step) ----------------
// z<2 (Q,K): MFMA operands SWAPPED (A=W, B=X) so reg-index j spans d -> ushort4 stores
//            into [bh][s][d] bf16. Q pre-scaled by inv_s*log2e via Wq/bq.
// z=2 (V):   normal order; writes TRANSPOSED+pi-PERMUTED [bh][d][s'] f16,
//            s' = s with bits[5:4]<->[3:2] swapped.
__launch_bounds__(256)
__global__ void qkv_gemm(const u16* __restrict__ X, const u16* __restrict__ C,
                         const u16* __restrict__ W0, const u16* __restrict__ W1, const u16* __restrict__ W2,
                         const float* __restrict__ b0, const float* __restrict__ b1, const float* __restrict__ b2,
                         u16* __restrict__ Qo, u16* __restrict__ Ko, u16* __restrict__ Vo, float qscl) {
    const int z = blockIdx.z;
    const u16* A    = (z == 0) ? X  : C;
    const u16* W    = (z == 0) ? W0 : (z == 1) ? W1 : W2;
    const float* bi = (z == 0) ? b0 : (z == 1) ? b1 : b2;
    u16* out        = (z == 0) ? Qo : (z == 1) ? Ko : Vo;
    const float bscl = (z == 0) ? qscl : 1.0f;

    __shared__ u16 As[2][128 * 64];
    __shared__ u16 Bs[2][128 * 64];

    const int tid  = threadIdx.x;
    const int lane = tid & 63;
    const int wid  = tid >> 6;
    const int wr = wid >> 1, wc = wid & 1;
    const int l15 = lane & 15, lh = lane >> 4;
    const int mBase = blockIdx.x * 128;
    const int nBase = blockIdx.y * 128;

    size_t aSrc[4], bSrc[4]; int ldsOffG[4];
    #pragma unroll
    for (int i = 0; i < 4; ++i) {
        int L = wid * 512 + i * 2048 + lane * 8;
        int row = L >> 6;
        int col = (L & 63) ^ ((row & 7) << 3);
        aSrc[i] = (size_t)(mBase + row) * KDIM + col;
        bSrc[i] = (size_t)(nBase + row) * KDIM + col;
        ldsOffG[i] = wid * 512 + i * 2048;
    }

    f32x4 acc[4][4] = {};

    // prologue: stage K-step 0 into buffer 0
    #pragma unroll
    for (int i = 0; i < 4; ++i) {
        GLOAD_LDS16(&A[aSrc[i]], &As[0][ldsOffG[i]]);
        GLOAD_LDS16(&W[bSrc[i]], &Bs[0][ldsOffG[i]]);
    }

    const int NIT = KDIM / 64;
    for (int it = 0; it < NIT; ++it) {
        const int cur = it & 1;
        __syncthreads();  // drains gload_lds: buf[cur] ready
        if (it + 1 < NIT) {
            const int kb = (it + 1) * 64;
            #pragma unroll
            for (int i = 0; i < 4; ++i) {
                GLOAD_LDS16(&A[aSrc[i] + kb], &As[cur ^ 1][ldsOffG[i]]);
                GLOAD_LDS16(&W[bSrc[i] + kb], &Bs[cur ^ 1][ldsOffG[i]]);
            }
        }
        #pragma unroll
        for (int kk = 0; kk < 2; ++kk) {
            s16x8 xf[4], wf[4];
            #pragma unroll
            for (int m = 0; m < 4; ++m)
                xf[m] = *(const s16x8*)(&As[cur][SWZ(wr * 64 + m * 16 + l15, kk * 32 + lh * 8)]);
            #pragma unroll
            for (int n = 0; n < 4; ++n)
                wf[n] = *(const s16x8*)(&Bs[cur][SWZ(wc * 64 + n * 16 + l15, kk * 32 + lh * 8)]);
            if (z < 2) {  // wave-uniform branch: swapped operands (D: col=s-row, reg=d-col)
                #pragma unroll
                for (int m = 0; m < 4; ++m)
                    #pragma unroll
                    for (int n = 0; n < 4; ++n)
                        acc[m][n] = __builtin_amdgcn_mfma_f32_16x16x32_bf16(wf[n], xf[m], acc[m][n], 0, 0, 0);
            } else {
                #pragma unroll
                for (int m = 0; m < 4; ++m)
                    #pragma unroll
                    for (int n = 0; n < 4; ++n)
                        acc[m][n] = __builtin_amdgcn_mfma_f32_16x16x32_bf16(xf[m], wf[n], acc[m][n], 0, 0, 0);
            }
        }
    }

    if (z < 2) {
        // D[col=l15 -> s within m-block][reg j -> d within n-block]: ushort4 per (m,n)
        #pragma unroll
        for (int m = 0; m < 4; ++m) {
            int sg = mBase + wr * 64 + m * 16 + l15;
            int b = sg >> 11, s = sg & 2047;
            #pragma unroll
            for (int n = 0; n < 4; ++n) {
                int d0 = nBase + wc * 64 + n * 16 + lh * 4;
                int h = d0 >> 6, d = d0 & 63;
                float4 bv = *(const float4*)(&bi[d0]);
                ushort4 o;
                o.x = f2bf(acc[m][n][0] + bv.x * bscl);
                o.y = f2bf(acc[m][n][1] + bv.y * bscl);
                o.z = f2bf(acc[m][n][2] + bv.z * bscl);
                o.w = f2bf(acc[m][n][3] + bv.w * bscl);
                *(ushort4*)(&out[(((size_t)(b * NHEADS + h) * SEQ + s) << 6) + d]) = o;
            }
        }
    } else {
        // V: [bh][d][s'] f16, s' = pi(s); 4 consecutive s -> ushort4.
        #pragma unroll
        for (int m = 0; m < 4; ++m) {
            #pragma unroll
            for (int n = 0; n < 4; ++n) {
                int colg = nBase + wc * 64 + n * 16 + l15;
                float bv = bi[colg];
                int h = colg >> 6, d = colg & 63;
                int rowg0 = mBase + wr * 64 + m * 16 + lh * 4;
                int b = rowg0 >> 11, s = rowg0 & 2047;
                int sp = (s & ~0x3C) | (((s >> 2) & 3) << 4) | (((s >> 4) & 3) << 2);
                ushort4 o;
                o.x = f2h(acc[m][n][0] + bv);
                o.y = f2h(acc[m][n][1] + bv);
                o.z = f2h(acc[m][n][2] + bv);
                o.w = f2h(acc[m][n][3] + bv);
                *(ushort4*)(&out[(((size_t)(b * NHEADS + h) * 64 + d) << 11) + sp]) = o;
            }
        }
    }
}

// ---------------- flash attention (swapped-QK^T, register softmax, exp2 domain) ----------------
// grid: (SEQ/128, NBH, SPLIT?2:1). 8 waves x 16 q-rows (q = lane&15). KV tile = 64, dbuf,
// one barrier per tile. Mask staged to LDS once, folded in as MFMA C-init.
// Ballot-first defer-max; lazy lrun (cross-lane reduce once after the loop).
template<bool SPLIT>
__launch_bounds__(512)
__global__ void attn_kernel(const u16* __restrict__ Qg, const u16* __restrict__ Kg,
                            const u16* __restrict__ Vg,
                            const float* __restrict__ maskL, float* __restrict__ out,
                            float* __restrict__ Opart, float* __restrict__ MLpart) {
    __shared__ u16 Ks[2][64 * 64];
    __shared__ u16 Vt[2][64 * 64];
    __shared__ float maskLds[2048];

    const int tid  = threadIdx.x;
    const int lane = tid & 63;
    const int wid  = tid >> 6;
    const int bh = blockIdx.y;
    const int b = bh / NHEADS;
    const int h = bh % NHEADS;
    const int q0 = blockIdx.x * 128 + wid * 16;
    const int l15 = lane & 15, lh = lane >> 4;
    const int z = SPLIT ? blockIdx.z : 0;
    const int NT = SPLIT ? (SEQ / 128) : (SEQ / 64);
    const int tile0 = z * NT;

    // mask slice -> LDS once (NT*64 floats)
    for (int i = tid * 4; i < NT * 64; i += 512 * 4)
        *(float4*)(&maskLds[i]) = *(const float4*)(&maskL[(size_t)b * SEQ + (tile0 << 6) + i]);

    // staging: 512 threads x 16B = full 64x64 u16 tile in one gload round.
    const int srow = tid >> 3;
    const int scol = ((tid & 7) * 8) ^ ((srow & 7) << 3);
    const size_t kSrc = (((size_t)bh * SEQ + srow) << 6) + scol + ((size_t)tile0 << 12);
    const size_t vSrc = (((size_t)bh * 64 + srow) << 11) + scol + (size_t)tile0 * 64;
    const int ldsBase = wid * 512;   // u16 units; lane*8 added by HW

    s16x8 qf[2];
    #pragma unroll
    for (int kk = 0; kk < 2; ++kk)
        qf[kk] = *(const s16x8*)(&Qg[(((size_t)bh * SEQ + q0 + l15) << 6) + kk * 32 + lh * 8]);

    f32x4 oacc[4] = {};           // O^T frags: oacc[nd][j] = O[q=l15][d=nd*16+lh*4+j]
    float mrun = -1e30f, lrun = 0.f;   // lrun is per-lane partial (lazy reduce)

    GLOAD_LDS16(&Kg[kSrc], &Ks[0][ldsBase]);
    GLOAD_LDS16(&Vg[vSrc], &Vt[0][ldsBase]);

    for (int t = 0; t < NT; ++t) {
        const int cur = t & 1;
        __syncthreads();
        if (t + 1 < NT) {
            GLOAD_LDS16(&Kg[kSrc + ((size_t)(t + 1) << 12)], &Ks[cur ^ 1][ldsBase]);
            GLOAD_LDS16(&Vg[vSrc + (size_t)(t + 1) * 64],    &Vt[cur ^ 1][ldsBase]);
        }

        // C-init = mask (broadcast LDS read), then S^T = mfma(K, Q) accumulates on top
        f32x4 sacc[4];
        #pragma unroll
        for (int n = 0; n < 4; ++n) {
            float4 mv = *(const float4*)(&maskLds[t * 64 + n * 16 + lh * 4]);
            sacc[n][0] = mv.x; sacc[n][1] = mv.y; sacc[n][2] = mv.z; sacc[n][3] = mv.w;
        }
        __builtin_amdgcn_s_setprio(1);
        #pragma unroll
        for (int kk = 0; kk < 2; ++kk) {
            #pragma unroll
            for (int n = 0; n < 4; ++n) {
                s16x8 kf = *(const s16x8*)(&Ks[cur][SWZ(n * 16 + l15, kk * 32 + lh * 8)]);
                sacc[n] = __builtin_amdgcn_mfma_f32_16x16x32_bf16(kf, qf[kk], sacc[n], 0, 0, 0);
            }
        }
        __builtin_amdgcn_s_setprio(0);

        // lane-local max; cross-lane reduce only when rescale might be needed
        float tmax = sacc[0][0];
        #pragma unroll
        for (int n = 0; n < 4; ++n)
            #pragma unroll
            for (int j = 0; j < 4; ++j)
                tmax = fmaxf(tmax, sacc[n][j]);

        if (!__all(tmax - mrun <= 11.0f)) {
            float rmax = fmaxf(tmax, __shfl_xor(tmax, 16));
            rmax = fmaxf(rmax, __shfl_xor(rmax, 32));
            float mnew = fmaxf(mrun, rmax);
            float alpha = __builtin_amdgcn_exp2f(mrun - mnew);
            lrun *= alpha;
            #pragma unroll
            for (int nd = 0; nd < 4; ++nd)
                #pragma unroll
                for (int j = 0; j < 4; ++j)
                    oacc[nd][j] *= alpha;
            mrun = mnew;
        }

        f16x4 pf[4];   // B-frag (16x16x16): k = lh*4 + e == S^T D-layout
        #pragma unroll
        for (int n = 0; n < 4; ++n) {
            float p0 = __builtin_amdgcn_exp2f(sacc[n][0] - mrun);
            float p1 = __builtin_amdgcn_exp2f(sacc[n][1] - mrun);
            float p2 = __builtin_amdgcn_exp2f(sacc[n][2] - mrun);
            float p3 = __builtin_amdgcn_exp2f(sacc[n][3] - mrun);
            lrun += (p0 + p1) + (p2 + p3);
            pf[n] = pack4(p0, p1, p2, p3);
        }

        // PV: one 16B read covers frags n=2kk,2kk+1 (pi-permuted V layout)
        __builtin_amdgcn_s_setprio(1);
        #pragma unroll
        for (int kk = 0; kk < 2; ++kk) {
            #pragma unroll
            for (int nd = 0; nd < 4; ++nd) {
                s16x8 v2 = *(const s16x8*)(&Vt[cur][SWZ(nd * 16 + l15, lh * 16 + kk * 8)]);
                union { s16x8 s8; f16x4 h4[2]; } u; u.s8 = v2;
                oacc[nd] = __builtin_amdgcn_mfma_f32_16x16x16f16(u.h4[0], pf[2 * kk],     oacc[nd], 0, 0, 0);
                oacc[nd] = __builtin_amdgcn_mfma_f32_16x16x16f16(u.h4[1], pf[2 * kk + 1], oacc[nd], 0, 0, 0);
            }
        }
        __builtin_amdgcn_s_setprio(0);
    }

    // lazy lrun: reduce across the 4 lh groups sharing each q
    lrun += __shfl_xor(lrun, 16);
    lrun += __shfl_xor(lrun, 32);

    const float inv = 1.0f / lrun;
    const int s = q0 + l15;
    if (!SPLIT) {
        #pragma unroll
        for (int nd = 0; nd < 4; ++nd) {
            float4 o;
            o.x = oacc[nd][0] * inv; o.y = oacc[nd][1] * inv;
            o.z = oacc[nd][2] * inv; o.w = oacc[nd][3] * inv;
            *(float4*)(&out[(size_t)(b * SEQ + s) * (NHEADS * 64) + h * 64 + nd * 16 + lh * 4]) = o;
        }
    } else {
        const size_t rbase = ((size_t)(z * NBH + bh) * SEQ + s);
        #pragma unroll
        for (int nd = 0; nd < 4; ++nd) {
            float4 o;
            o.x = oacc[nd][0] * inv; o.y = oacc[nd][1] * inv;
            o.z = oacc[nd][2] * inv; o.w = oacc[nd][3] * inv;
            *(float4*)(&Opart[rbase * 64 + nd * 16 + lh * 4]) = o;
        }
        if (lh == 0)
            *(float2*)(&MLpart[rbase * 2]) = make_float2(mrun, lrun);
    }
}

// ---------------- split-KV combine ----------------
__global__ void combine_kernel(const float* __restrict__ Opart, const float* __restrict__ MLpart,
                               float* __restrict__ out) {
    int gid = blockIdx.x * 256 + threadIdx.x;   // NBH*SEQ*16 = 786432 threads
    int row = gid >> 4, d4 = gid & 15;
    float2 ml0 = ((const float2*)MLpart)[row];
    float2 ml1 = ((const float2*)MLpart)[NBH * SEQ + row];
    float m = fmaxf(ml0.x, ml1.x);
    float w0 = __builtin_amdgcn_exp2f(ml0.x - m) * ml0.y;
    float w1 = __builtin_amdgcn_exp2f(ml1.x - m) * ml1.y;
    float inv = 1.0f / (w0 + w1);
    w0 *= inv; w1 *= inv;
    float4 o0 = *(const float4*)(&Opart[(size_t)row * 64 + d4 * 4]);
    float4 o1 = *(const float4*)(&Opart[(size_t)NBH * SEQ * 64 + (size_t)row * 64 + d4 * 4]);
    float4 o;
    o.x = o0.x * w0 + o1.x * w1; o.y = o0.y * w0 + o1.y * w1;
    o.z = o0.z * w0 + o1.z * w1; o.w = o0.w * w0 + o1.w * w1;
    int bh = row >> 11, s = row & 2047;
    int b = bh / NHEADS, hh = bh % NHEADS;
    *(float4*)(&out[(size_t)(b * SEQ + s) * (NHEADS * 64) + hh * 64 + d4 * 4]) = o;
}

extern "C" void kernel_launch(void* const* d_in, const int* in_sizes, int n_in,
                              void* d_out, int out_size, void* d_ws, size_t ws_size,
                              hipStream_t stream) {
    const float* hidden  = (const float*)d_in[0];
    const float* context = (const float*)d_in[1];
    const float* mask    = (const float*)d_in[2];
    const float* Wq = (const float*)d_in[3];
    const float* bq = (const float*)d_in[4];
    const float* Wk = (const float*)d_in[5];
    const float* bk = (const float*)d_in[6];
    const float* Wv = (const float*)d_in[7];
    const float* bv = (const float*)d_in[8];
    float* out = (float*)d_out;

    char* ws = (char*)d_ws;
    const size_t XSZ = (size_t)4096 * 768 * 2;
    const size_t WSZ = (size_t)768 * 768 * 2;
    u16* X16  = (u16*)(ws);
    u16* C16  = (u16*)(ws + XSZ);
    u16* W16q = (u16*)(ws + 2 * XSZ);
    u16* W16k = (u16*)(ws + 2 * XSZ + WSZ);
    u16* W16v = (u16*)(ws + 2 * XSZ + 2 * WSZ);
    u16* Q16  = (u16*)(ws + 2 * XSZ + 3 * WSZ);
    u16* K16  = (u16*)(ws + 3 * XSZ + 3 * WSZ);
    u16* V16  = (u16*)(ws + 4 * XSZ + 3 * WSZ);    // f16, [bh][d][s'] pi-permuted
    const size_t MASKL_OFF = 5 * XSZ + 3 * WSZ;    // 34,996,224
    float* maskL = (float*)(ws + MASKL_OFF);
    const size_t OPART_OFF = MASKL_OFF + 2 * SEQ * sizeof(float) + 256;
    float* Opart = (float*)(ws + OPART_OFF);                        // 25.2 MB
    const size_t ML_OFF = OPART_OFF + (size_t)2 * NBH * SEQ * 64 * 4;
    float* MLpart = (float*)(ws + ML_OFF);                          // 786 KB
    const size_t WS_NEED_SPLIT = ML_OFF + (size_t)2 * NBH * SEQ * 2 * 4;

    const float qscl = (float)((1.0 / sqrt(64.0 + 1e-5)) * 1.44269504088896);

    const int n4x = 4096 * 768 / 4;
    const int n4w = 768 * 768 / 4;
    cvt6_kernel<<<dim3((n4x + 255) / 256, 1, 6), 256, 0, stream>>>(
        hidden, context, Wq, Wk, Wv, mask,
        X16, C16, W16q, W16k, W16v, maskL, n4x, n4w, qscl);

    qkv_gemm<<<dim3(4096 / 128, 768 / 128, 3), 256, 0, stream>>>(
        X16, C16, W16q, W16k, W16v, bq, bk, bv, Q16, K16, V16, qscl);

    if (ws_size >= WS_NEED_SPLIT) {
        attn_kernel<true><<<dim3(SEQ / 128, NBH, 2), 512, 0, stream>>>(
            Q16, K16, V16, maskL, out, Opart, MLpart);
        combine_kernel<<<(NBH * SEQ * 16) / 256, 256, 0, stream>>>(Opart, MLpart, out);
    } else {
        attn_kernel<false><<<dim3(SEQ / 128, NBH, 1), 512, 0, stream>>>(
            Q16, K16, V16, maskL, out, Opart, MLpart);
    }
}